// Round 4
// baseline (755.568 us; speedup 1.0000x reference)
//
#include <hip/hip_runtime.h>

#define BB 8
#define NN 2048
#define LL 1280
#define HH 160
#define BN (BB*NN)          // 16384
#define NO (2*HH + LL)      // 1600
#define SHIFT 40.0f

typedef __attribute__((ext_vector_type(8))) short short8;
typedef __attribute__((ext_vector_type(4))) float floatx4;

__device__ __forceinline__ unsigned short f2bf(float f) {
    unsigned int u = __builtin_bit_cast(unsigned int, f);
    u = (u + 0x7FFFu + ((u >> 16) & 1u)) >> 16;
    return (unsigned short)u;
}
__device__ __forceinline__ float bf2f(unsigned short h) {
    unsigned int u = ((unsigned int)h) << 16;
    return __builtin_bit_cast(float, u);
}
__device__ __forceinline__ void split2(float f, unsigned short& hi, unsigned short& lo) {
    hi = f2bf(f);
    lo = f2bf(f - bf2f(hi));
}

// ---------------- cast weights ----------------
__global__ __launch_bounds__(256) void cast_w(
    const float* __restrict__ Wq, const float* __restrict__ Wk, const float* __restrict__ Wv,
    unsigned short* __restrict__ wqk_h, unsigned short* __restrict__ wqk_l,
    unsigned short* __restrict__ wv)
{
    int o = blockIdx.x;   // 0..1599
    if (o < 2*HH) {
        const float* src = (o < HH) ? (Wq + (size_t)o * LL) : (Wk + (size_t)(o - HH) * LL);
        unsigned short* dh = wqk_h + (size_t)o * LL;
        unsigned short* dl = wqk_l + (size_t)o * LL;
        for (int c = threadIdx.x; c < LL; c += 256) {
            unsigned short h, l;
            split2(src[c], h, l);
            dh[c] = h; dl[c] = l;
        }
    } else {
        const float* src = Wv + (size_t)(o - 2*HH) * LL;
        unsigned short* dst = wv + (size_t)(o - 2*HH) * LL;
        for (int c = threadIdx.x * 4; c < LL; c += 256 * 4) {
            float4 f = *(const float4*)(src + c);
            ushort4 u;
            u.x = f2bf(f.x); u.y = f2bf(f.y); u.z = f2bf(f.z); u.w = f2bf(f.w);
            *(ushort4*)(dst + c) = u;
        }
    }
}

// ---------------- Kernel 1a: q,k projection, bf16x2 (3-product MFMA) ----------------
__global__ __launch_bounds__(256, 2) void proj_qk(
    const float* __restrict__ x,
    const unsigned short* __restrict__ wh, const unsigned short* __restrict__ wl,
    const float* __restrict__ bq, const float* __restrict__ bk,
    unsigned short* __restrict__ qh, unsigned short* __restrict__ ql,
    unsigned short* __restrict__ kh, unsigned short* __restrict__ kl)
{
    __shared__ __align__(16) unsigned short Ah[128 * 40];
    __shared__ __align__(16) unsigned short Al[128 * 40];
    __shared__ __align__(16) unsigned short Bh[64 * 40];
    __shared__ __align__(16) unsigned short Bl[64 * 40];

    const int o0 = blockIdx.x * 64;
    const int m0 = blockIdx.y * 128;
    const int tid = threadIdx.x;
    const int wave = tid >> 6, lane = tid & 63;
    const int l15 = lane & 15, l4 = lane >> 4;

    floatx4 acc[2][4] = {};

    const int sr = tid >> 2;          // 0..63
    const int sc = (tid & 3) * 8;     // 0/8/16/24

    for (int k0 = 0; k0 < LL; k0 += 32) {
        __syncthreads();
        #pragma unroll
        for (int h = 0; h < 2; h++) {
            int r = sr + h * 64;
            const float* xp = x + (size_t)(m0 + r) * LL + k0 + sc;
            float4 f0 = *(const float4*)xp;
            float4 f1 = *(const float4*)(xp + 4);
            float fv[8] = {f0.x, f0.y, f0.z, f0.w, f1.x, f1.y, f1.z, f1.w};
            short8 h8, l8;
            #pragma unroll
            for (int i = 0; i < 8; i++) {
                unsigned short hh, lll;
                split2(fv[i], hh, lll);
                h8[i] = (short)hh; l8[i] = (short)lll;
            }
            *(short8*)&Ah[r * 40 + sc] = h8;
            *(short8*)&Al[r * 40 + sc] = l8;
        }
        *(short8*)&Bh[sr * 40 + sc] = *(const short8*)&wh[(size_t)(o0 + sr) * LL + k0 + sc];
        *(short8*)&Bl[sr * 40 + sc] = *(const short8*)&wl[(size_t)(o0 + sr) * LL + k0 + sc];
        __syncthreads();

        short8 ah0 = *(const short8*)&Ah[(wave * 32 + l15) * 40 + l4 * 8];
        short8 ah1 = *(const short8*)&Ah[(wave * 32 + 16 + l15) * 40 + l4 * 8];
        short8 al0 = *(const short8*)&Al[(wave * 32 + l15) * 40 + l4 * 8];
        short8 al1 = *(const short8*)&Al[(wave * 32 + 16 + l15) * 40 + l4 * 8];
        #pragma unroll
        for (int ct = 0; ct < 4; ct++) {
            short8 bh8 = *(const short8*)&Bh[(ct * 16 + l15) * 40 + l4 * 8];
            short8 bl8 = *(const short8*)&Bl[(ct * 16 + l15) * 40 + l4 * 8];
            acc[0][ct] = __builtin_amdgcn_mfma_f32_16x16x32_bf16(ah0, bh8, acc[0][ct], 0, 0, 0);
            acc[0][ct] = __builtin_amdgcn_mfma_f32_16x16x32_bf16(al0, bh8, acc[0][ct], 0, 0, 0);
            acc[0][ct] = __builtin_amdgcn_mfma_f32_16x16x32_bf16(ah0, bl8, acc[0][ct], 0, 0, 0);
            acc[1][ct] = __builtin_amdgcn_mfma_f32_16x16x32_bf16(ah1, bh8, acc[1][ct], 0, 0, 0);
            acc[1][ct] = __builtin_amdgcn_mfma_f32_16x16x32_bf16(al1, bh8, acc[1][ct], 0, 0, 0);
            acc[1][ct] = __builtin_amdgcn_mfma_f32_16x16x32_bf16(ah1, bl8, acc[1][ct], 0, 0, 0);
        }
    }

    #pragma unroll
    for (int rt = 0; rt < 2; rt++)
        #pragma unroll
        for (int ct = 0; ct < 4; ct++)
            #pragma unroll
            for (int r = 0; r < 4; r++) {
                int m = m0 + wave * 32 + rt * 16 + l4 * 4 + r;
                int o = o0 + ct * 16 + l15;
                float val = acc[rt][ct][r] + ((o < HH) ? bq[o] : bk[o - HH]);
                unsigned short vh, vl;
                split2(val, vh, vl);
                if (o < HH) {
                    qh[(size_t)m * HH + o] = vh;
                    ql[(size_t)m * HH + o] = vl;
                } else {
                    kh[(size_t)m * HH + (o - HH)] = vh;
                    kl[(size_t)m * HH + (o - HH)] = vl;
                }
            }
}

// ---------------- Kernel 1b: v projection, bf16 MFMA, transposed output ----------------
__global__ __launch_bounds__(256, 2) void proj_v(
    const float* __restrict__ x, const unsigned short* __restrict__ wv,
    const float* __restrict__ bv, unsigned short* __restrict__ vt)
{
    __shared__ __align__(16) unsigned char smem[128 * 136 * 2];
    unsigned short* As = (unsigned short*)smem;      // [128][40]
    unsigned short* Bs = As + 128 * 40;              // [128][40]

    const int o0 = blockIdx.x * 128;
    const int m0 = blockIdx.y * 128;
    const int tid = threadIdx.x;
    const int wave = tid >> 6, lane = tid & 63;
    const int l15 = lane & 15, l4 = lane >> 4;

    floatx4 acc[2][8] = {};

    const int sr = tid >> 2;
    const int sc = (tid & 3) * 8;

    for (int k0 = 0; k0 < LL; k0 += 32) {
        __syncthreads();
        #pragma unroll
        for (int h = 0; h < 2; h++) {
            int r = sr + h * 64;
            const float* xp = x + (size_t)(m0 + r) * LL + k0 + sc;
            float4 f0 = *(const float4*)xp;
            float4 f1 = *(const float4*)(xp + 4);
            short8 h8;
            h8[0]=(short)f2bf(f0.x); h8[1]=(short)f2bf(f0.y); h8[2]=(short)f2bf(f0.z); h8[3]=(short)f2bf(f0.w);
            h8[4]=(short)f2bf(f1.x); h8[5]=(short)f2bf(f1.y); h8[6]=(short)f2bf(f1.z); h8[7]=(short)f2bf(f1.w);
            *(short8*)&As[r * 40 + sc] = h8;
            *(short8*)&Bs[r * 40 + sc] =
                *(const short8*)&wv[(size_t)(o0 + r) * LL + k0 + sc];
        }
        __syncthreads();
        short8 af0 = *(const short8*)&As[(wave * 32 + l15) * 40 + l4 * 8];
        short8 af1 = *(const short8*)&As[(wave * 32 + 16 + l15) * 40 + l4 * 8];
        #pragma unroll
        for (int ct = 0; ct < 8; ct++) {
            short8 bf = *(const short8*)&Bs[(ct * 16 + l15) * 40 + l4 * 8];
            acc[0][ct] = __builtin_amdgcn_mfma_f32_16x16x32_bf16(af0, bf, acc[0][ct], 0, 0, 0);
            acc[1][ct] = __builtin_amdgcn_mfma_f32_16x16x32_bf16(af1, bf, acc[1][ct], 0, 0, 0);
        }
    }

    __syncthreads();
    unsigned short* trs = (unsigned short*)smem;     // [128 col][136] transpose buf

    #pragma unroll
    for (int rt = 0; rt < 2; rt++)
        #pragma unroll
        for (int ct = 0; ct < 8; ct++)
            #pragma unroll
            for (int r = 0; r < 4; r++) {
                int ml = wave * 32 + rt * 16 + l4 * 4 + r;
                int cl = ct * 16 + l15;
                trs[cl * 136 + ml] = f2bf(acc[rt][ct][r] + bv[o0 + cl]);
            }
    __syncthreads();
    {
        int bidx = m0 >> 11;
        int n0 = m0 & 2047;
        int cl = tid >> 1;
        int f = o0 + cl;
        unsigned short* dst = vt + ((size_t)bidx * LL + f) * NN + n0 + (tid & 1) * 64;
        const unsigned short* srcr = trs + cl * 136 + (tid & 1) * 64;
        #pragma unroll
        for (int i = 0; i < 8; i++)
            *(short8*)(dst + i * 8) = *(const short8*)(srcr + i * 8);
    }
}

// ---------------- Kernel 2a: S = exp(QK^T - SHIFT), row sums ----------------
__global__ __launch_bounds__(256, 2) void s_exp(
    const unsigned short* __restrict__ qhp, const unsigned short* __restrict__ qlp,
    const unsigned short* __restrict__ khp, const unsigned short* __restrict__ klp,
    unsigned short* __restrict__ P, float* __restrict__ Lsum)
{
    __shared__ float sums[4][32];
    const int b  = blockIdx.y;
    const int i0 = blockIdx.x * 32;
    const int tid = threadIdx.x;
    const int wave = tid >> 6, lane = tid & 63;
    const int l15 = lane & 15, l4 = lane >> 4;

    short8 aqh[2][5], aql[2][5];
    #pragma unroll
    for (int rt = 0; rt < 2; rt++) {
        const size_t rowb = ((size_t)b * NN + i0 + rt * 16 + l15) * HH + l4 * 8;
        #pragma unroll
        for (int ks = 0; ks < 5; ks++) {
            aqh[rt][ks] = *(const short8*)&qhp[rowb + ks * 32];
            aql[rt][ks] = *(const short8*)&qlp[rowb + ks * 32];
        }
    }

    float sr[2][4] = {};
    const unsigned short* khB = khp + (size_t)b * NN * HH;
    const unsigned short* klB = klp + (size_t)b * NN * HH;
    unsigned short* Pb = P + (size_t)b * NN * NN;

    for (int c0 = 0; c0 < NN; c0 += 256) {
        const int jb = c0 + wave * 64;      // wave's 64-col stripe
        #pragma unroll
        for (int ct = 0; ct < 4; ct++) {
            const int tok = jb + ct * 16 + l15;
            const size_t kbase = (size_t)tok * HH + l4 * 8;
            floatx4 a0[3] = {{0,0,0,0},{0,0,0,0},{0,0,0,0}};
            floatx4 a1[3] = {{0,0,0,0},{0,0,0,0},{0,0,0,0}};
            #pragma unroll
            for (int ks = 0; ks < 5; ks++) {
                short8 bh = *(const short8*)&khB[kbase + ks * 32];
                short8 bl = *(const short8*)&klB[kbase + ks * 32];
                a0[0] = __builtin_amdgcn_mfma_f32_16x16x32_bf16(aqh[0][ks], bh, a0[0], 0, 0, 0);
                a0[1] = __builtin_amdgcn_mfma_f32_16x16x32_bf16(aql[0][ks], bh, a0[1], 0, 0, 0);
                a0[2] = __builtin_amdgcn_mfma_f32_16x16x32_bf16(aqh[0][ks], bl, a0[2], 0, 0, 0);
                a1[0] = __builtin_amdgcn_mfma_f32_16x16x32_bf16(aqh[1][ks], bh, a1[0], 0, 0, 0);
                a1[1] = __builtin_amdgcn_mfma_f32_16x16x32_bf16(aql[1][ks], bh, a1[1], 0, 0, 0);
                a1[2] = __builtin_amdgcn_mfma_f32_16x16x32_bf16(aqh[1][ks], bl, a1[2], 0, 0, 0);
            }
            #pragma unroll
            for (int r = 0; r < 4; r++) {
                float e0 = a0[0][r] + a0[1][r] + a0[2][r];
                float e1 = a1[0][r] + a1[1][r] + a1[2][r];
                unsigned short pb0 = f2bf(__expf(e0 - SHIFT));
                unsigned short pb1 = f2bf(__expf(e1 - SHIFT));
                Pb[(size_t)(i0 + l4 * 4 + r) * NN + tok] = pb0;
                Pb[(size_t)(i0 + 16 + l4 * 4 + r) * NN + tok] = pb1;
                sr[0][r] += bf2f(pb0);
                sr[1][r] += bf2f(pb1);
            }
        }
    }

    #pragma unroll
    for (int rt = 0; rt < 2; rt++)
        #pragma unroll
        for (int r = 0; r < 4; r++) {
            float v = sr[rt][r];
            v += __shfl_xor(v, 1);
            v += __shfl_xor(v, 2);
            v += __shfl_xor(v, 4);
            v += __shfl_xor(v, 8);
            if (l15 == 0) sums[wave][rt * 16 + l4 * 4 + r] = v;
        }
    __syncthreads();
    if (tid < 32)
        Lsum[(size_t)b * NN + i0 + tid] =
            sums[0][tid] + sums[1][tid] + sums[2][tid] + sums[3][tid];
}

// ---------------- Kernel 2b v5: no-LDS direct-fragment GEMM ----------------
// Diagnosis (rounds 0-3): the 32x128-wave LDS-staged structure is LDS-read-
// BW-bound: 10 KB LDS reads per 16 MFMA/wave -> 4 SIMDs need ~320-480 cyc of
// the shared LDS unit per 78 cyc of MFMA -> MfmaUtil capped at ~20% (matches
// 19-20% across all 3 scheduling variants). Fix: read MFMA fragments DIRECTLY
// from global/L2 (pattern proven in s_exp's K-operand): no LDS, no barriers,
// waves fully independent, compiler software-pipelines.
//   - 128-thread blocks (2 waves), wave tile 64x128: acc[4][8] (128 VGPR).
//   - 1-deep register prefetch (next K-step's 12 frags loaded before MFMAs).
//   - New bound: L2 feed 12 KB/wave-step -> MfmaUtil cap ~42% (2x old cap).
//   - XCD swizzle kept: b = bid&7, n-fastest tile order (L2 locality).
__global__ __launch_bounds__(128, 2) void pv_gemm(
    const unsigned short* __restrict__ P, const unsigned short* __restrict__ vt,
    const float* __restrict__ Lsum,
    const float* __restrict__ x, float* __restrict__ out)
{
    const int p0 = blockIdx.x;          // 0..1279
    const int b  = p0 & 7;              // one batch per XCD
    const int t  = p0 >> 3;             // 0..159
    const int n0 = (t % 10) * 128;
    const int m0 = (t / 10) * 128;

    const int tid  = threadIdx.x;
    const int wave = tid >> 6, lane = tid & 63;
    const int l15 = lane & 15, l4 = lane >> 4;

    const unsigned short* __restrict__ Pb  = P  + (size_t)b * NN * NN;
    const unsigned short* __restrict__ vtb = vt + (size_t)b * LL * NN;

    // per-lane element offsets (fit 32-bit: max ~4.2M shorts)
    unsigned aoff[4], boff[8];
    #pragma unroll
    for (int rt = 0; rt < 4; rt++)
        aoff[rt] = (unsigned)(m0 + wave * 64 + rt * 16 + l15) * NN + l4 * 8;
    #pragma unroll
    for (int ct = 0; ct < 8; ct++)
        boff[ct] = (unsigned)(n0 + ct * 16 + l15) * NN + l4 * 8;

    floatx4 acc[4][8] = {};

    // preload K-step 0
    short8 aP[4], bP[8];
    #pragma unroll
    for (int rt = 0; rt < 4; rt++) aP[rt] = *(const short8*)(Pb + aoff[rt]);
    #pragma unroll
    for (int ct = 0; ct < 8; ct++) bP[ct] = *(const short8*)(vtb + boff[ct]);

    #pragma unroll 2
    for (int k0 = 32; k0 < NN; k0 += 32) {
        short8 aN[4], bN[8];
        #pragma unroll
        for (int rt = 0; rt < 4; rt++) aN[rt] = *(const short8*)(Pb + aoff[rt] + k0);
        #pragma unroll
        for (int ct = 0; ct < 8; ct++) bN[ct] = *(const short8*)(vtb + boff[ct] + k0);
        #pragma unroll
        for (int rt = 0; rt < 4; rt++)
            #pragma unroll
            for (int ct = 0; ct < 8; ct++)
                acc[rt][ct] = __builtin_amdgcn_mfma_f32_16x16x32_bf16(aP[rt], bP[ct], acc[rt][ct], 0, 0, 0);
        #pragma unroll
        for (int rt = 0; rt < 4; rt++) aP[rt] = aN[rt];
        #pragma unroll
        for (int ct = 0; ct < 8; ct++) bP[ct] = bN[ct];
    }
    #pragma unroll
    for (int rt = 0; rt < 4; rt++)
        #pragma unroll
        for (int ct = 0; ct < 8; ct++)
            acc[rt][ct] = __builtin_amdgcn_mfma_f32_16x16x32_bf16(aP[rt], bP[ct], acc[rt][ct], 0, 0, 0);

    float linv[4][4];
    #pragma unroll
    for (int rt = 0; rt < 4; rt++)
        #pragma unroll
        for (int r = 0; r < 4; r++)
            linv[rt][r] = 1.0f / Lsum[(size_t)b * NN + m0 + wave * 64 + rt * 16 + l4 * 4 + r];

    #pragma unroll
    for (int rt = 0; rt < 4; rt++)
        #pragma unroll
        for (int ct = 0; ct < 8; ct++)
            #pragma unroll
            for (int r = 0; r < 4; r++) {
                int row = m0 + wave * 64 + rt * 16 + l4 * 4 + r;
                int col = n0 + ct * 16 + l15;
                size_t idx = ((size_t)b * NN + row) * LL + col;
                out[idx] = acc[rt][ct][r] * linv[rt][r] + x[idx];
            }
}

extern "C" void kernel_launch(void* const* d_in, const int* in_sizes, int n_in,
                              void* d_out, int out_size, void* d_ws, size_t ws_size,
                              hipStream_t stream) {
    const float* x  = (const float*)d_in[0];
    const float* Wq = (const float*)d_in[1];
    const float* bq = (const float*)d_in[2];
    const float* Wk = (const float*)d_in[3];
    const float* bk = (const float*)d_in[4];
    const float* Wv = (const float*)d_in[5];
    const float* bv = (const float*)d_in[6];
    float* out = (float*)d_out;

    // ws layout (~135 MB)
    unsigned short* wqk_h = (unsigned short*)d_ws;            // [320][LL]
    unsigned short* wqk_l = wqk_h + (size_t)2*HH * LL;        // [320][LL]
    unsigned short* wv    = wqk_l + (size_t)2*HH * LL;        // [LL][LL]
    unsigned short* qh    = wv    + (size_t)LL * LL;          // [BN][HH]
    unsigned short* ql    = qh    + (size_t)BN * HH;
    unsigned short* kh    = ql    + (size_t)BN * HH;
    unsigned short* kl    = kh    + (size_t)BN * HH;
    unsigned short* vt    = kl    + (size_t)BN * HH;          // [BB][LL][NN]
    unsigned short* P     = vt    + (size_t)BB * LL * NN;     // [BB][NN][NN]
    float*          Lsum  = (float*)(P + (size_t)BB * NN * NN); // [BN]

    cast_w<<<dim3(NO), dim3(256), 0, stream>>>(Wq, Wk, Wv, wqk_h, wqk_l, wv);

    dim3 gqk(2*HH / 64, BN / 128);         // (5, 128)
    proj_qk<<<gqk, dim3(256), 0, stream>>>(x, wqk_h, wqk_l, bq, bk, qh, ql, kh, kl);

    dim3 gv(LL / 128, BN / 128);           // (10, 128)
    proj_v<<<gv, dim3(256), 0, stream>>>(x, wv, bv, vt);

    dim3 gs(NN / 32, BB);                  // (64, 8)
    s_exp<<<gs, dim3(256), 0, stream>>>(qh, ql, kh, kl, P, Lsum);

    // flat 1280 blocks of 128 threads: b = bid&7 (batch per XCD), n-fastest
    pv_gemm<<<dim3(1280), dim3(128), 0, stream>>>(P, vt, Lsum, x, out);
}

// Round 5
// 627.329 us; speedup vs baseline: 1.2044x; 1.2044x over previous
//
#include <hip/hip_runtime.h>

#define BB 8
#define NN 2048
#define LL 1280
#define HH 160
#define BN (BB*NN)          // 16384
#define NO (2*HH + LL)      // 1600
#define SHIFT 40.0f

typedef __attribute__((ext_vector_type(8))) short short8;
typedef __attribute__((ext_vector_type(4))) float floatx4;

__device__ __forceinline__ unsigned short f2bf(float f) {
    unsigned int u = __builtin_bit_cast(unsigned int, f);
    u = (u + 0x7FFFu + ((u >> 16) & 1u)) >> 16;
    return (unsigned short)u;
}
__device__ __forceinline__ float bf2f(unsigned short h) {
    unsigned int u = ((unsigned int)h) << 16;
    return __builtin_bit_cast(float, u);
}
__device__ __forceinline__ void split2(float f, unsigned short& hi, unsigned short& lo) {
    hi = f2bf(f);
    lo = f2bf(f - bf2f(hi));
}

// ---------------- cast weights ----------------
__global__ __launch_bounds__(256) void cast_w(
    const float* __restrict__ Wq, const float* __restrict__ Wk, const float* __restrict__ Wv,
    unsigned short* __restrict__ wqk_h, unsigned short* __restrict__ wqk_l,
    unsigned short* __restrict__ wv)
{
    int o = blockIdx.x;   // 0..1599
    if (o < 2*HH) {
        const float* src = (o < HH) ? (Wq + (size_t)o * LL) : (Wk + (size_t)(o - HH) * LL);
        unsigned short* dh = wqk_h + (size_t)o * LL;
        unsigned short* dl = wqk_l + (size_t)o * LL;
        for (int c = threadIdx.x; c < LL; c += 256) {
            unsigned short h, l;
            split2(src[c], h, l);
            dh[c] = h; dl[c] = l;
        }
    } else {
        const float* src = Wv + (size_t)(o - 2*HH) * LL;
        unsigned short* dst = wv + (size_t)(o - 2*HH) * LL;
        for (int c = threadIdx.x * 4; c < LL; c += 256 * 4) {
            float4 f = *(const float4*)(src + c);
            ushort4 u;
            u.x = f2bf(f.x); u.y = f2bf(f.y); u.z = f2bf(f.z); u.w = f2bf(f.w);
            *(ushort4*)(dst + c) = u;
        }
    }
}

// ---------------- Kernel 1a: q,k projection, bf16x2 (3-product MFMA) ----------------
__global__ __launch_bounds__(256, 2) void proj_qk(
    const float* __restrict__ x,
    const unsigned short* __restrict__ wh, const unsigned short* __restrict__ wl,
    const float* __restrict__ bq, const float* __restrict__ bk,
    unsigned short* __restrict__ qh, unsigned short* __restrict__ ql,
    unsigned short* __restrict__ kh, unsigned short* __restrict__ kl)
{
    __shared__ __align__(16) unsigned short Ah[128 * 40];
    __shared__ __align__(16) unsigned short Al[128 * 40];
    __shared__ __align__(16) unsigned short Bh[64 * 40];
    __shared__ __align__(16) unsigned short Bl[64 * 40];

    const int o0 = blockIdx.x * 64;
    const int m0 = blockIdx.y * 128;
    const int tid = threadIdx.x;
    const int wave = tid >> 6, lane = tid & 63;
    const int l15 = lane & 15, l4 = lane >> 4;

    floatx4 acc[2][4] = {};

    const int sr = tid >> 2;          // 0..63
    const int sc = (tid & 3) * 8;     // 0/8/16/24

    for (int k0 = 0; k0 < LL; k0 += 32) {
        __syncthreads();
        #pragma unroll
        for (int h = 0; h < 2; h++) {
            int r = sr + h * 64;
            const float* xp = x + (size_t)(m0 + r) * LL + k0 + sc;
            float4 f0 = *(const float4*)xp;
            float4 f1 = *(const float4*)(xp + 4);
            float fv[8] = {f0.x, f0.y, f0.z, f0.w, f1.x, f1.y, f1.z, f1.w};
            short8 h8, l8;
            #pragma unroll
            for (int i = 0; i < 8; i++) {
                unsigned short hh, lll;
                split2(fv[i], hh, lll);
                h8[i] = (short)hh; l8[i] = (short)lll;
            }
            *(short8*)&Ah[r * 40 + sc] = h8;
            *(short8*)&Al[r * 40 + sc] = l8;
        }
        *(short8*)&Bh[sr * 40 + sc] = *(const short8*)&wh[(size_t)(o0 + sr) * LL + k0 + sc];
        *(short8*)&Bl[sr * 40 + sc] = *(const short8*)&wl[(size_t)(o0 + sr) * LL + k0 + sc];
        __syncthreads();

        short8 ah0 = *(const short8*)&Ah[(wave * 32 + l15) * 40 + l4 * 8];
        short8 ah1 = *(const short8*)&Ah[(wave * 32 + 16 + l15) * 40 + l4 * 8];
        short8 al0 = *(const short8*)&Al[(wave * 32 + l15) * 40 + l4 * 8];
        short8 al1 = *(const short8*)&Al[(wave * 32 + 16 + l15) * 40 + l4 * 8];
        #pragma unroll
        for (int ct = 0; ct < 4; ct++) {
            short8 bh8 = *(const short8*)&Bh[(ct * 16 + l15) * 40 + l4 * 8];
            short8 bl8 = *(const short8*)&Bl[(ct * 16 + l15) * 40 + l4 * 8];
            acc[0][ct] = __builtin_amdgcn_mfma_f32_16x16x32_bf16(ah0, bh8, acc[0][ct], 0, 0, 0);
            acc[0][ct] = __builtin_amdgcn_mfma_f32_16x16x32_bf16(al0, bh8, acc[0][ct], 0, 0, 0);
            acc[0][ct] = __builtin_amdgcn_mfma_f32_16x16x32_bf16(ah0, bl8, acc[0][ct], 0, 0, 0);
            acc[1][ct] = __builtin_amdgcn_mfma_f32_16x16x32_bf16(ah1, bh8, acc[1][ct], 0, 0, 0);
            acc[1][ct] = __builtin_amdgcn_mfma_f32_16x16x32_bf16(al1, bh8, acc[1][ct], 0, 0, 0);
            acc[1][ct] = __builtin_amdgcn_mfma_f32_16x16x32_bf16(ah1, bl8, acc[1][ct], 0, 0, 0);
        }
    }

    #pragma unroll
    for (int rt = 0; rt < 2; rt++)
        #pragma unroll
        for (int ct = 0; ct < 4; ct++)
            #pragma unroll
            for (int r = 0; r < 4; r++) {
                int m = m0 + wave * 32 + rt * 16 + l4 * 4 + r;
                int o = o0 + ct * 16 + l15;
                float val = acc[rt][ct][r] + ((o < HH) ? bq[o] : bk[o - HH]);
                unsigned short vh, vl;
                split2(val, vh, vl);
                if (o < HH) {
                    qh[(size_t)m * HH + o] = vh;
                    ql[(size_t)m * HH + o] = vl;
                } else {
                    kh[(size_t)m * HH + (o - HH)] = vh;
                    kl[(size_t)m * HH + (o - HH)] = vl;
                }
            }
}

// ---------------- Kernel 1b: v projection, frag-major output ----------------
// vt is now stored FRAGMENT-MAJOR for pv_gemm's B operand:
//   vt_f[b][c16][kstep][lane][8], lane = l4*16 + l15,
//   element (f, j): c16=f>>4, l15=f&15, kstep=j>>5, l4=(j>>3)&3, e=j&7
//   addr = b*LL*NN + (f>>4)*32768 + (j>>5)*512 + ((j>>3)&3)*128 + (f&15)*8 + (j&7)
__global__ __launch_bounds__(256, 2) void proj_v(
    const float* __restrict__ x, const unsigned short* __restrict__ wv,
    const float* __restrict__ bv, unsigned short* __restrict__ vt)
{
    __shared__ __align__(16) unsigned char smem[128 * 136 * 2];
    unsigned short* As = (unsigned short*)smem;      // [128][40]
    unsigned short* Bs = As + 128 * 40;              // [128][40]

    const int o0 = blockIdx.x * 128;
    const int m0 = blockIdx.y * 128;
    const int tid = threadIdx.x;
    const int wave = tid >> 6, lane = tid & 63;
    const int l15 = lane & 15, l4 = lane >> 4;

    floatx4 acc[2][8] = {};

    const int sr = tid >> 2;
    const int sc = (tid & 3) * 8;

    for (int k0 = 0; k0 < LL; k0 += 32) {
        __syncthreads();
        #pragma unroll
        for (int h = 0; h < 2; h++) {
            int r = sr + h * 64;
            const float* xp = x + (size_t)(m0 + r) * LL + k0 + sc;
            float4 f0 = *(const float4*)xp;
            float4 f1 = *(const float4*)(xp + 4);
            short8 h8;
            h8[0]=(short)f2bf(f0.x); h8[1]=(short)f2bf(f0.y); h8[2]=(short)f2bf(f0.z); h8[3]=(short)f2bf(f0.w);
            h8[4]=(short)f2bf(f1.x); h8[5]=(short)f2bf(f1.y); h8[6]=(short)f2bf(f1.z); h8[7]=(short)f2bf(f1.w);
            *(short8*)&As[r * 40 + sc] = h8;
            *(short8*)&Bs[r * 40 + sc] =
                *(const short8*)&wv[(size_t)(o0 + r) * LL + k0 + sc];
        }
        __syncthreads();
        short8 af0 = *(const short8*)&As[(wave * 32 + l15) * 40 + l4 * 8];
        short8 af1 = *(const short8*)&As[(wave * 32 + 16 + l15) * 40 + l4 * 8];
        #pragma unroll
        for (int ct = 0; ct < 8; ct++) {
            short8 bf = *(const short8*)&Bs[(ct * 16 + l15) * 40 + l4 * 8];
            acc[0][ct] = __builtin_amdgcn_mfma_f32_16x16x32_bf16(af0, bf, acc[0][ct], 0, 0, 0);
            acc[1][ct] = __builtin_amdgcn_mfma_f32_16x16x32_bf16(af1, bf, acc[1][ct], 0, 0, 0);
        }
    }

    __syncthreads();
    unsigned short* trs = (unsigned short*)smem;     // [128 col][136] transpose buf

    #pragma unroll
    for (int rt = 0; rt < 2; rt++)
        #pragma unroll
        for (int ct = 0; ct < 8; ct++)
            #pragma unroll
            for (int r = 0; r < 4; r++) {
                int ml = wave * 32 + rt * 16 + l4 * 4 + r;
                int cl = ct * 16 + l15;
                trs[cl * 136 + ml] = f2bf(acc[rt][ct][r] + bv[o0 + cl]);
            }
    __syncthreads();
    {
        int bidx = m0 >> 11;
        int nb0 = m0 & 2047;
        int cl = tid >> 1;
        int f = o0 + cl;
        const unsigned short* srcr = trs + cl * 136 + (tid & 1) * 64;
        unsigned short* dstF = vt + (size_t)bidx * LL * NN
                             + (size_t)(f >> 4) * 32768 + (f & 15) * 8;
        int nb = nb0 + (tid & 1) * 64;
        #pragma unroll
        for (int i = 0; i < 8; i++) {
            int n = nb + i * 8;
            *(short8*)(dstF + (size_t)(n >> 5) * 512 + ((n >> 3) & 3) * 128)
                = *(const short8*)(srcr + i * 8);
        }
    }
}

// ---------------- Kernel 2a: S = exp(QK^T - SHIFT), frag-major P ----------------
// P is now stored FRAGMENT-MAJOR for pv_gemm's A operand:
//   P_f[b][m16][kstep][lane][8], lane = l4*16 + l15,
//   element (row, tok): m16=row>>4, l15=row&15, kstep=tok>>5, l4=(tok>>3)&3, e=tok&7
//   addr = b*NN*NN + (row>>4)*32768 + (tok>>5)*512 + ((tok>>3)&3)*128 + (row&15)*8 + (tok&7)
__global__ __launch_bounds__(256, 2) void s_exp(
    const unsigned short* __restrict__ qhp, const unsigned short* __restrict__ qlp,
    const unsigned short* __restrict__ khp, const unsigned short* __restrict__ klp,
    unsigned short* __restrict__ P, float* __restrict__ Lsum)
{
    __shared__ float sums[4][32];
    const int b  = blockIdx.y;
    const int i0 = blockIdx.x * 32;
    const int tid = threadIdx.x;
    const int wave = tid >> 6, lane = tid & 63;
    const int l15 = lane & 15, l4 = lane >> 4;

    short8 aqh[2][5], aql[2][5];
    #pragma unroll
    for (int rt = 0; rt < 2; rt++) {
        const size_t rowb = ((size_t)b * NN + i0 + rt * 16 + l15) * HH + l4 * 8;
        #pragma unroll
        for (int ks = 0; ks < 5; ks++) {
            aqh[rt][ks] = *(const short8*)&qhp[rowb + ks * 32];
            aql[rt][ks] = *(const short8*)&qlp[rowb + ks * 32];
        }
    }

    float sr[2][4] = {};
    const unsigned short* khB = khp + (size_t)b * NN * HH;
    const unsigned short* klB = klp + (size_t)b * NN * HH;
    unsigned short* Pb = P + (size_t)b * NN * NN + (size_t)(i0 >> 4) * 32768;

    for (int c0 = 0; c0 < NN; c0 += 256) {
        const int jb = c0 + wave * 64;      // wave's 64-col stripe
        #pragma unroll
        for (int ct = 0; ct < 4; ct++) {
            const int tok = jb + ct * 16 + l15;
            const size_t kbase = (size_t)tok * HH + l4 * 8;
            floatx4 a0[3] = {{0,0,0,0},{0,0,0,0},{0,0,0,0}};
            floatx4 a1[3] = {{0,0,0,0},{0,0,0,0},{0,0,0,0}};
            #pragma unroll
            for (int ks = 0; ks < 5; ks++) {
                short8 bh = *(const short8*)&khB[kbase + ks * 32];
                short8 bl = *(const short8*)&klB[kbase + ks * 32];
                a0[0] = __builtin_amdgcn_mfma_f32_16x16x32_bf16(aqh[0][ks], bh, a0[0], 0, 0, 0);
                a0[1] = __builtin_amdgcn_mfma_f32_16x16x32_bf16(aql[0][ks], bh, a0[1], 0, 0, 0);
                a0[2] = __builtin_amdgcn_mfma_f32_16x16x32_bf16(aqh[0][ks], bl, a0[2], 0, 0, 0);
                a1[0] = __builtin_amdgcn_mfma_f32_16x16x32_bf16(aqh[1][ks], bh, a1[0], 0, 0, 0);
                a1[1] = __builtin_amdgcn_mfma_f32_16x16x32_bf16(aql[1][ks], bh, a1[1], 0, 0, 0);
                a1[2] = __builtin_amdgcn_mfma_f32_16x16x32_bf16(aqh[1][ks], bl, a1[2], 0, 0, 0);
            }
            // frag-major address parts for this tok
            const size_t tbase = (size_t)(tok >> 5) * 512 + ((tok >> 3) & 3) * 128 + (tok & 7);
            #pragma unroll
            for (int r = 0; r < 4; r++) {
                float e0 = a0[0][r] + a0[1][r] + a0[2][r];
                float e1 = a1[0][r] + a1[1][r] + a1[2][r];
                unsigned short pb0 = f2bf(__expf(e0 - SHIFT));
                unsigned short pb1 = f2bf(__expf(e1 - SHIFT));
                Pb[tbase + (l4 * 4 + r) * 8] = pb0;            // rows i0..i0+15
                Pb[tbase + (l4 * 4 + r) * 8 + 32768] = pb1;    // rows i0+16..i0+31
                sr[0][r] += bf2f(pb0);
                sr[1][r] += bf2f(pb1);
            }
        }
    }

    #pragma unroll
    for (int rt = 0; rt < 2; rt++)
        #pragma unroll
        for (int r = 0; r < 4; r++) {
            float v = sr[rt][r];
            v += __shfl_xor(v, 1);
            v += __shfl_xor(v, 2);
            v += __shfl_xor(v, 4);
            v += __shfl_xor(v, 8);
            if (l15 == 0) sums[wave][rt * 16 + l4 * 4 + r] = v;
        }
    __syncthreads();
    if (tid < 32)
        Lsum[(size_t)b * NN + i0 + tid] =
            sums[0][tid] + sums[1][tid] + sums[2][tid] + sums[3][tid];
}

// ---------------- Kernel 2b v6: frag-major no-LDS GEMM ----------------
// Rounds 0-4 taught: LDS-staged frags cap at ~20% MfmaUtil (LDS issue BW);
// global row-major frags cap at ~10% (16-line gathers through TA). Fix:
// P and vt are OUR workspace -> store them fragment-major so every MFMA
// operand load is ONE fully-coalesced 1KB wave load (base + lane*16B) from
// L2. No LDS, no barriers, 1-deep register prefetch, waves independent.
// 128 threads (2 waves), wave tile 64x128 (acc 4x8), XCD batch swizzle.
__global__ __launch_bounds__(128, 2) void pv_gemm(
    const unsigned short* __restrict__ P, const unsigned short* __restrict__ vt,
    const float* __restrict__ Lsum,
    const float* __restrict__ x, float* __restrict__ out)
{
    const int p0 = blockIdx.x;          // 0..1279
    const int b  = p0 & 7;              // one batch per XCD
    const int t  = p0 >> 3;             // 0..159
    const int n0 = (t % 10) * 128;
    const int m0 = (t / 10) * 128;

    const int tid  = threadIdx.x;
    const int wave = tid >> 6, lane = tid & 63;
    const int l15 = lane & 15, l4 = lane >> 4;

    const unsigned short* __restrict__ Pb  = P  + (size_t)b * NN * NN;
    const unsigned short* __restrict__ vtb = vt + (size_t)b * LL * NN;

    // frag-major offsets (shorts, fit 32-bit)
    unsigned aoff[4], boff[8];
    #pragma unroll
    for (int rt = 0; rt < 4; rt++)
        aoff[rt] = (unsigned)((m0 >> 4) + wave * 4 + rt) * 32768u + lane * 8;
    #pragma unroll
    for (int ct = 0; ct < 8; ct++)
        boff[ct] = (unsigned)((n0 >> 4) + ct) * 32768u + lane * 8;

    floatx4 acc[4][8] = {};

    short8 aP[4], bP[8];
    #pragma unroll
    for (int rt = 0; rt < 4; rt++) aP[rt] = *(const short8*)(Pb + aoff[rt]);
    #pragma unroll
    for (int ct = 0; ct < 8; ct++) bP[ct] = *(const short8*)(vtb + boff[ct]);

    #pragma unroll 2
    for (int ks = 1; ks < 64; ks++) {
        short8 aN[4], bN[8];
        #pragma unroll
        for (int rt = 0; rt < 4; rt++) aN[rt] = *(const short8*)(Pb + aoff[rt] + ks * 512u);
        #pragma unroll
        for (int ct = 0; ct < 8; ct++) bN[ct] = *(const short8*)(vtb + boff[ct] + ks * 512u);
        #pragma unroll
        for (int rt = 0; rt < 4; rt++)
            #pragma unroll
            for (int ct = 0; ct < 8; ct++)
                acc[rt][ct] = __builtin_amdgcn_mfma_f32_16x16x32_bf16(aP[rt], bP[ct], acc[rt][ct], 0, 0, 0);
        #pragma unroll
        for (int rt = 0; rt < 4; rt++) aP[rt] = aN[rt];
        #pragma unroll
        for (int ct = 0; ct < 8; ct++) bP[ct] = bN[ct];
    }
    #pragma unroll
    for (int rt = 0; rt < 4; rt++)
        #pragma unroll
        for (int ct = 0; ct < 8; ct++)
            acc[rt][ct] = __builtin_amdgcn_mfma_f32_16x16x32_bf16(aP[rt], bP[ct], acc[rt][ct], 0, 0, 0);

    float linv[4][4];
    #pragma unroll
    for (int rt = 0; rt < 4; rt++)
        #pragma unroll
        for (int r = 0; r < 4; r++)
            linv[rt][r] = 1.0f / Lsum[(size_t)b * NN + m0 + wave * 64 + rt * 16 + l4 * 4 + r];

    #pragma unroll
    for (int rt = 0; rt < 4; rt++)
        #pragma unroll
        for (int ct = 0; ct < 8; ct++)
            #pragma unroll
            for (int r = 0; r < 4; r++) {
                int row = m0 + wave * 64 + rt * 16 + l4 * 4 + r;
                int col = n0 + ct * 16 + l15;
                size_t idx = ((size_t)b * NN + row) * LL + col;
                out[idx] = acc[rt][ct][r] * linv[rt][r] + x[idx];
            }
}

extern "C" void kernel_launch(void* const* d_in, const int* in_sizes, int n_in,
                              void* d_out, int out_size, void* d_ws, size_t ws_size,
                              hipStream_t stream) {
    const float* x  = (const float*)d_in[0];
    const float* Wq = (const float*)d_in[1];
    const float* bq = (const float*)d_in[2];
    const float* Wk = (const float*)d_in[3];
    const float* bk = (const float*)d_in[4];
    const float* Wv = (const float*)d_in[5];
    const float* bv = (const float*)d_in[6];
    float* out = (float*)d_out;

    // ws layout (~135 MB)
    unsigned short* wqk_h = (unsigned short*)d_ws;            // [320][LL]
    unsigned short* wqk_l = wqk_h + (size_t)2*HH * LL;        // [320][LL]
    unsigned short* wv    = wqk_l + (size_t)2*HH * LL;        // [LL][LL]
    unsigned short* qh    = wv    + (size_t)LL * LL;          // [BN][HH]
    unsigned short* ql    = qh    + (size_t)BN * HH;
    unsigned short* kh    = ql    + (size_t)BN * HH;
    unsigned short* kl    = kh    + (size_t)BN * HH;
    unsigned short* vt    = kl    + (size_t)BN * HH;          // [BB][LL*NN] frag-major
    unsigned short* P     = vt    + (size_t)BB * LL * NN;     // [BB][NN*NN] frag-major
    float*          Lsum  = (float*)(P + (size_t)BB * NN * NN); // [BN]

    cast_w<<<dim3(NO), dim3(256), 0, stream>>>(Wq, Wk, Wv, wqk_h, wqk_l, wv);

    dim3 gqk(2*HH / 64, BN / 128);         // (5, 128)
    proj_qk<<<gqk, dim3(256), 0, stream>>>(x, wqk_h, wqk_l, bq, bk, qh, ql, kh, kl);

    dim3 gv(LL / 128, BN / 128);           // (10, 128)
    proj_v<<<gv, dim3(256), 0, stream>>>(x, wv, bv, vt);

    dim3 gs(NN / 32, BB);                  // (64, 8)
    s_exp<<<gs, dim3(256), 0, stream>>>(qh, ql, kh, kl, P, Lsum);

    // flat 1280 blocks of 128 threads: b = bid&7 (batch per XCD), n-fastest
    pv_gemm<<<dim3(1280), dim3(128), 0, stream>>>(P, vt, Lsum, x, out);
}

// Round 6
// 566.062 us; speedup vs baseline: 1.3348x; 1.1082x over previous
//
#include <hip/hip_runtime.h>

#define BB 8
#define NN 2048
#define LL 1280
#define HH 160
#define BN (BB*NN)          // 16384
#define NO (2*HH + LL)      // 1600
#define SHIFT 40.0f

typedef __attribute__((ext_vector_type(8))) short short8;
typedef __attribute__((ext_vector_type(4))) float floatx4;

__device__ __forceinline__ unsigned short f2bf(float f) {
    unsigned int u = __builtin_bit_cast(unsigned int, f);
    u = (u + 0x7FFFu + ((u >> 16) & 1u)) >> 16;
    return (unsigned short)u;
}
__device__ __forceinline__ float bf2f(unsigned short h) {
    unsigned int u = ((unsigned int)h) << 16;
    return __builtin_bit_cast(float, u);
}
__device__ __forceinline__ void split2(float f, unsigned short& hi, unsigned short& lo) {
    hi = f2bf(f);
    lo = f2bf(f - bf2f(hi));
}

// q/k fragment-major layout (for s_exp's MFMA operands):
//   F(m, h) = (m>>4)*2560 + (h>>5)*512 + ((h>>3)&3)*128 + (m&15)*8 + (h&7)
// so a 16-row x 32-h fragment is one contiguous 1KB wave-load at
// base(m16, ks) + lane*8, lane = ((h>>3)&3)*16 + (m&15).

// ---------------- cast weights ----------------
__global__ __launch_bounds__(256) void cast_w(
    const float* __restrict__ Wq, const float* __restrict__ Wk, const float* __restrict__ Wv,
    unsigned short* __restrict__ wqk_h, unsigned short* __restrict__ wqk_l,
    unsigned short* __restrict__ wv)
{
    int o = blockIdx.x;   // 0..1599
    if (o < 2*HH) {
        const float* src = (o < HH) ? (Wq + (size_t)o * LL) : (Wk + (size_t)(o - HH) * LL);
        unsigned short* dh = wqk_h + (size_t)o * LL;
        unsigned short* dl = wqk_l + (size_t)o * LL;
        for (int c = threadIdx.x; c < LL; c += 256) {
            unsigned short h, l;
            split2(src[c], h, l);
            dh[c] = h; dl[c] = l;
        }
    } else {
        const float* src = Wv + (size_t)(o - 2*HH) * LL;
        unsigned short* dst = wv + (size_t)(o - 2*HH) * LL;
        for (int c = threadIdx.x * 4; c < LL; c += 256 * 4) {
            float4 f = *(const float4*)(src + c);
            ushort4 u;
            u.x = f2bf(f.x); u.y = f2bf(f.y); u.z = f2bf(f.z); u.w = f2bf(f.w);
            *(ushort4*)(dst + c) = u;
        }
    }
}

// ---------------- Kernel 1a: q,k projection -> frag-major q/k ----------------
__global__ __launch_bounds__(256, 2) void proj_qk(
    const float* __restrict__ x,
    const unsigned short* __restrict__ wh, const unsigned short* __restrict__ wl,
    const float* __restrict__ bq, const float* __restrict__ bk,
    unsigned short* __restrict__ qh, unsigned short* __restrict__ ql,
    unsigned short* __restrict__ kh, unsigned short* __restrict__ kl)
{
    __shared__ __align__(16) unsigned short Ah[128 * 40];
    __shared__ __align__(16) unsigned short Al[128 * 40];
    __shared__ __align__(16) unsigned short Bh[64 * 40];
    __shared__ __align__(16) unsigned short Bl[64 * 40];

    const int o0 = blockIdx.x * 64;
    const int m0 = blockIdx.y * 128;
    const int tid = threadIdx.x;
    const int wave = tid >> 6, lane = tid & 63;
    const int l15 = lane & 15, l4 = lane >> 4;

    floatx4 acc[2][4] = {};

    const int sr = tid >> 2;          // 0..63
    const int sc = (tid & 3) * 8;     // 0/8/16/24

    for (int k0 = 0; k0 < LL; k0 += 32) {
        __syncthreads();
        #pragma unroll
        for (int h = 0; h < 2; h++) {
            int r = sr + h * 64;
            const float* xp = x + (size_t)(m0 + r) * LL + k0 + sc;
            float4 f0 = *(const float4*)xp;
            float4 f1 = *(const float4*)(xp + 4);
            float fv[8] = {f0.x, f0.y, f0.z, f0.w, f1.x, f1.y, f1.z, f1.w};
            short8 h8, l8;
            #pragma unroll
            for (int i = 0; i < 8; i++) {
                unsigned short hh, lll;
                split2(fv[i], hh, lll);
                h8[i] = (short)hh; l8[i] = (short)lll;
            }
            *(short8*)&Ah[r * 40 + sc] = h8;
            *(short8*)&Al[r * 40 + sc] = l8;
        }
        *(short8*)&Bh[sr * 40 + sc] = *(const short8*)&wh[(size_t)(o0 + sr) * LL + k0 + sc];
        *(short8*)&Bl[sr * 40 + sc] = *(const short8*)&wl[(size_t)(o0 + sr) * LL + k0 + sc];
        __syncthreads();

        short8 ah0 = *(const short8*)&Ah[(wave * 32 + l15) * 40 + l4 * 8];
        short8 ah1 = *(const short8*)&Ah[(wave * 32 + 16 + l15) * 40 + l4 * 8];
        short8 al0 = *(const short8*)&Al[(wave * 32 + l15) * 40 + l4 * 8];
        short8 al1 = *(const short8*)&Al[(wave * 32 + 16 + l15) * 40 + l4 * 8];
        #pragma unroll
        for (int ct = 0; ct < 4; ct++) {
            short8 bh8 = *(const short8*)&Bh[(ct * 16 + l15) * 40 + l4 * 8];
            short8 bl8 = *(const short8*)&Bl[(ct * 16 + l15) * 40 + l4 * 8];
            acc[0][ct] = __builtin_amdgcn_mfma_f32_16x16x32_bf16(ah0, bh8, acc[0][ct], 0, 0, 0);
            acc[0][ct] = __builtin_amdgcn_mfma_f32_16x16x32_bf16(al0, bh8, acc[0][ct], 0, 0, 0);
            acc[0][ct] = __builtin_amdgcn_mfma_f32_16x16x32_bf16(ah0, bl8, acc[0][ct], 0, 0, 0);
            acc[1][ct] = __builtin_amdgcn_mfma_f32_16x16x32_bf16(ah1, bh8, acc[1][ct], 0, 0, 0);
            acc[1][ct] = __builtin_amdgcn_mfma_f32_16x16x32_bf16(al1, bh8, acc[1][ct], 0, 0, 0);
            acc[1][ct] = __builtin_amdgcn_mfma_f32_16x16x32_bf16(ah1, bl8, acc[1][ct], 0, 0, 0);
        }
    }

    #pragma unroll
    for (int rt = 0; rt < 2; rt++)
        #pragma unroll
        for (int ct = 0; ct < 4; ct++)
            #pragma unroll
            for (int r = 0; r < 4; r++) {
                int m = m0 + wave * 32 + rt * 16 + l4 * 4 + r;
                int o = o0 + ct * 16 + l15;
                float val = acc[rt][ct][r] + ((o < HH) ? bq[o] : bk[o - HH]);
                unsigned short vh, vl;
                split2(val, vh, vl);
                int oo = (o < HH) ? o : (o - HH);
                size_t fa = (size_t)(m >> 4) * 2560 + (oo >> 5) * 512
                          + ((oo >> 3) & 3) * 128 + (m & 15) * 8 + (oo & 7);
                if (o < HH) {
                    qh[fa] = vh;
                    ql[fa] = vl;
                } else {
                    kh[fa] = vh;
                    kl[fa] = vl;
                }
            }
}

// ---------------- Kernel 1b: v projection, bf16 MFMA, row-major vt ----------------
__global__ __launch_bounds__(256, 2) void proj_v(
    const float* __restrict__ x, const unsigned short* __restrict__ wv,
    const float* __restrict__ bv, unsigned short* __restrict__ vt)
{
    __shared__ __align__(16) unsigned char smem[128 * 136 * 2];
    unsigned short* As = (unsigned short*)smem;      // [128][40]
    unsigned short* Bs = As + 128 * 40;              // [128][40]

    const int o0 = blockIdx.x * 128;
    const int m0 = blockIdx.y * 128;
    const int tid = threadIdx.x;
    const int wave = tid >> 6, lane = tid & 63;
    const int l15 = lane & 15, l4 = lane >> 4;

    floatx4 acc[2][8] = {};

    const int sr = tid >> 2;
    const int sc = (tid & 3) * 8;

    for (int k0 = 0; k0 < LL; k0 += 32) {
        __syncthreads();
        #pragma unroll
        for (int h = 0; h < 2; h++) {
            int r = sr + h * 64;
            const float* xp = x + (size_t)(m0 + r) * LL + k0 + sc;
            float4 f0 = *(const float4*)xp;
            float4 f1 = *(const float4*)(xp + 4);
            short8 h8;
            h8[0]=(short)f2bf(f0.x); h8[1]=(short)f2bf(f0.y); h8[2]=(short)f2bf(f0.z); h8[3]=(short)f2bf(f0.w);
            h8[4]=(short)f2bf(f1.x); h8[5]=(short)f2bf(f1.y); h8[6]=(short)f2bf(f1.z); h8[7]=(short)f2bf(f1.w);
            *(short8*)&As[r * 40 + sc] = h8;
            *(short8*)&Bs[r * 40 + sc] =
                *(const short8*)&wv[(size_t)(o0 + r) * LL + k0 + sc];
        }
        __syncthreads();
        short8 af0 = *(const short8*)&As[(wave * 32 + l15) * 40 + l4 * 8];
        short8 af1 = *(const short8*)&As[(wave * 32 + 16 + l15) * 40 + l4 * 8];
        #pragma unroll
        for (int ct = 0; ct < 8; ct++) {
            short8 bf = *(const short8*)&Bs[(ct * 16 + l15) * 40 + l4 * 8];
            acc[0][ct] = __builtin_amdgcn_mfma_f32_16x16x32_bf16(af0, bf, acc[0][ct], 0, 0, 0);
            acc[1][ct] = __builtin_amdgcn_mfma_f32_16x16x32_bf16(af1, bf, acc[1][ct], 0, 0, 0);
        }
    }

    __syncthreads();
    unsigned short* trs = (unsigned short*)smem;     // [128 col][136] transpose buf

    #pragma unroll
    for (int rt = 0; rt < 2; rt++)
        #pragma unroll
        for (int ct = 0; ct < 8; ct++)
            #pragma unroll
            for (int r = 0; r < 4; r++) {
                int ml = wave * 32 + rt * 16 + l4 * 4 + r;
                int cl = ct * 16 + l15;
                trs[cl * 136 + ml] = f2bf(acc[rt][ct][r] + bv[o0 + cl]);
            }
    __syncthreads();
    {
        int bidx = m0 >> 11;
        int n0 = m0 & 2047;
        int cl = tid >> 1;
        int f = o0 + cl;
        unsigned short* dst = vt + ((size_t)bidx * LL + f) * NN + n0 + (tid & 1) * 64;
        const unsigned short* srcr = trs + cl * 136 + (tid & 1) * 64;
        #pragma unroll
        for (int i = 0; i < 8; i++)
            *(short8*)(dst + i * 8) = *(const short8*)(srcr + i * 8);
    }
}

// ---------------- Kernel 2a: S = exp(QK^T - SHIFT), frag-major q/k loads ----------------
// Q and K operand loads are now single coalesced 1KB wave-loads (frag-major
// layout written by proj_qk) instead of 16-line gathers (the round-4-diagnosed
// TA-serialization pathology, executed 640x per block here). P stays row-major.
__global__ __launch_bounds__(256, 2) void s_exp(
    const unsigned short* __restrict__ qhp, const unsigned short* __restrict__ qlp,
    const unsigned short* __restrict__ khp, const unsigned short* __restrict__ klp,
    unsigned short* __restrict__ P, float* __restrict__ Lsum)
{
    __shared__ float sums[4][32];
    const int b  = blockIdx.y;
    const int i0 = blockIdx.x * 32;
    const int tid = threadIdx.x;
    const int wave = tid >> 6, lane = tid & 63;
    const int l15 = lane & 15, l4 = lane >> 4;

    // resident A-frags: coalesced frag-major loads
    short8 aqh[2][5], aql[2][5];
    #pragma unroll
    for (int rt = 0; rt < 2; rt++) {
        const size_t rowb = (size_t)((b * NN + i0 + rt * 16) >> 4) * 2560 + lane * 8;
        #pragma unroll
        for (int ks = 0; ks < 5; ks++) {
            aqh[rt][ks] = *(const short8*)&qhp[rowb + ks * 512];
            aql[rt][ks] = *(const short8*)&qlp[rowb + ks * 512];
        }
    }

    float sr[2][4] = {};
    unsigned short* Pb = P + (size_t)b * NN * NN;

    for (int c0 = 0; c0 < NN; c0 += 256) {
        const int jb = c0 + wave * 64;      // wave's 64-col stripe
        #pragma unroll
        for (int ct = 0; ct < 4; ct++) {
            const int tok0 = jb + ct * 16;                 // multiple of 16
            const int tok  = tok0 + l15;
            const size_t kbase = (size_t)((b * NN + tok0) >> 4) * 2560 + lane * 8;
            floatx4 a0[3] = {{0,0,0,0},{0,0,0,0},{0,0,0,0}};
            floatx4 a1[3] = {{0,0,0,0},{0,0,0,0},{0,0,0,0}};
            #pragma unroll
            for (int ks = 0; ks < 5; ks++) {
                short8 bh = *(const short8*)&khp[kbase + ks * 512];
                short8 bl = *(const short8*)&klp[kbase + ks * 512];
                a0[0] = __builtin_amdgcn_mfma_f32_16x16x32_bf16(aqh[0][ks], bh, a0[0], 0, 0, 0);
                a0[1] = __builtin_amdgcn_mfma_f32_16x16x32_bf16(aql[0][ks], bh, a0[1], 0, 0, 0);
                a0[2] = __builtin_amdgcn_mfma_f32_16x16x32_bf16(aqh[0][ks], bl, a0[2], 0, 0, 0);
                a1[0] = __builtin_amdgcn_mfma_f32_16x16x32_bf16(aqh[1][ks], bh, a1[0], 0, 0, 0);
                a1[1] = __builtin_amdgcn_mfma_f32_16x16x32_bf16(aql[1][ks], bh, a1[1], 0, 0, 0);
                a1[2] = __builtin_amdgcn_mfma_f32_16x16x32_bf16(aqh[1][ks], bl, a1[2], 0, 0, 0);
            }
            #pragma unroll
            for (int r = 0; r < 4; r++) {
                float e0 = a0[0][r] + a0[1][r] + a0[2][r];
                float e1 = a1[0][r] + a1[1][r] + a1[2][r];
                unsigned short pb0 = f2bf(__expf(e0 - SHIFT));
                unsigned short pb1 = f2bf(__expf(e1 - SHIFT));
                Pb[(size_t)(i0 + l4 * 4 + r) * NN + tok] = pb0;
                Pb[(size_t)(i0 + 16 + l4 * 4 + r) * NN + tok] = pb1;
                sr[0][r] += bf2f(pb0);
                sr[1][r] += bf2f(pb1);
            }
        }
    }

    #pragma unroll
    for (int rt = 0; rt < 2; rt++)
        #pragma unroll
        for (int r = 0; r < 4; r++) {
            float v = sr[rt][r];
            v += __shfl_xor(v, 1);
            v += __shfl_xor(v, 2);
            v += __shfl_xor(v, 4);
            v += __shfl_xor(v, 8);
            if (l15 == 0) sums[wave][rt * 16 + l4 * 4 + r] = v;
        }
    __syncthreads();
    if (tid < 32)
        Lsum[(size_t)b * NN + i0 + tid] =
            sums[0][tid] + sums[1][tid] + sums[2][tid] + sums[3][tid];
}

// ---------------- Kernel 2b: out = (P x V)/L + x  (round-0 structure) ----------------
// Session-best structure restored verbatim (reg-staged, stride-40 LDS,
// 128x128 tile, BK=32): 177 us / ~486 TF at this shape. Only change: the
// grid is flattened with batch-per-XCD decode (T1) — block body untouched.
__global__ __launch_bounds__(256, 2) void pv_gemm(
    const unsigned short* __restrict__ P, const unsigned short* __restrict__ vt,
    const float* __restrict__ Lsum,
    const float* __restrict__ x, float* __restrict__ out)
{
    __shared__ __align__(16) unsigned short As[128 * 40];
    __shared__ __align__(16) unsigned short Bs[128 * 40];

    const int p0 = blockIdx.x;          // 0..1279
    const int b  = p0 & 7;              // one batch per XCD
    const int t  = p0 >> 3;             // 0..159
    const int n0 = (t % 10) * 128;
    const int m0 = (t / 10) * 128;

    const int tid = threadIdx.x;
    const int wave = tid >> 6, lane = tid & 63;
    const int l15 = lane & 15, l4 = lane >> 4;

    const unsigned short* Pb  = P  + (size_t)b * NN * NN;
    const unsigned short* vtb = vt + (size_t)b * LL * NN;

    floatx4 acc[2][8] = {};
    const int str = tid >> 2;
    const int stc = (tid & 3) * 8;

    for (int k0 = 0; k0 < NN; k0 += 32) {
        __syncthreads();
        #pragma unroll
        for (int h = 0; h < 2; h++) {
            int r = str + h * 64;
            *(short8*)&As[r * 40 + stc] = *(const short8*)&Pb[(size_t)(m0 + r) * NN + k0 + stc];
            *(short8*)&Bs[r * 40 + stc] = *(const short8*)&vtb[(size_t)(n0 + r) * NN + k0 + stc];
        }
        __syncthreads();
        short8 af0 = *(const short8*)&As[(wave * 32 + l15) * 40 + l4 * 8];
        short8 af1 = *(const short8*)&As[(wave * 32 + 16 + l15) * 40 + l4 * 8];
        #pragma unroll
        for (int ct = 0; ct < 8; ct++) {
            short8 bf = *(const short8*)&Bs[(ct * 16 + l15) * 40 + l4 * 8];
            acc[0][ct] = __builtin_amdgcn_mfma_f32_16x16x32_bf16(af0, bf, acc[0][ct], 0, 0, 0);
            acc[1][ct] = __builtin_amdgcn_mfma_f32_16x16x32_bf16(af1, bf, acc[1][ct], 0, 0, 0);
        }
    }

    float linv[2][4];
    #pragma unroll
    for (int rt = 0; rt < 2; rt++)
        #pragma unroll
        for (int r = 0; r < 4; r++)
            linv[rt][r] = 1.0f / Lsum[(size_t)b * NN + m0 + wave * 32 + rt * 16 + l4 * 4 + r];

    #pragma unroll
    for (int rt = 0; rt < 2; rt++)
        #pragma unroll
        for (int ct = 0; ct < 8; ct++)
            #pragma unroll
            for (int r = 0; r < 4; r++) {
                int row = m0 + wave * 32 + rt * 16 + l4 * 4 + r;
                int col = n0 + ct * 16 + l15;
                size_t idx = ((size_t)b * NN + row) * LL + col;
                out[idx] = acc[rt][ct][r] * linv[rt][r] + x[idx];
            }
}

extern "C" void kernel_launch(void* const* d_in, const int* in_sizes, int n_in,
                              void* d_out, int out_size, void* d_ws, size_t ws_size,
                              hipStream_t stream) {
    const float* x  = (const float*)d_in[0];
    const float* Wq = (const float*)d_in[1];
    const float* bq = (const float*)d_in[2];
    const float* Wk = (const float*)d_in[3];
    const float* bk = (const float*)d_in[4];
    const float* Wv = (const float*)d_in[5];
    const float* bv = (const float*)d_in[6];
    float* out = (float*)d_out;

    // ws layout (~135 MB)
    unsigned short* wqk_h = (unsigned short*)d_ws;            // [320][LL]
    unsigned short* wqk_l = wqk_h + (size_t)2*HH * LL;        // [320][LL]
    unsigned short* wv    = wqk_l + (size_t)2*HH * LL;        // [LL][LL]
    unsigned short* qh    = wv    + (size_t)LL * LL;          // [BN][HH] frag-major
    unsigned short* ql    = qh    + (size_t)BN * HH;
    unsigned short* kh    = ql    + (size_t)BN * HH;
    unsigned short* kl    = kh    + (size_t)BN * HH;
    unsigned short* vt    = kl    + (size_t)BN * HH;          // [BB][LL][NN] row-major
    unsigned short* P     = vt    + (size_t)BB * LL * NN;     // [BB][NN][NN] row-major
    float*          Lsum  = (float*)(P + (size_t)BB * NN * NN); // [BN]

    cast_w<<<dim3(NO), dim3(256), 0, stream>>>(Wq, Wk, Wv, wqk_h, wqk_l, wv);

    dim3 gqk(2*HH / 64, BN / 128);         // (5, 128)
    proj_qk<<<gqk, dim3(256), 0, stream>>>(x, wqk_h, wqk_l, bq, bk, qh, ql, kh, kl);

    dim3 gv(LL / 128, BN / 128);           // (10, 128)
    proj_v<<<gv, dim3(256), 0, stream>>>(x, wv, bv, vt);

    dim3 gs(NN / 32, BB);                  // (64, 8)
    s_exp<<<gs, dim3(256), 0, stream>>>(qh, ql, kh, kl, P, Lsum);

    // flat 1280 blocks: b = bid&7 (batch per XCD), t = bid>>3 -> (n,m) tile
    pv_gemm<<<dim3(1280), dim3(256), 0, stream>>>(P, vt, Lsum, x, out);
}

// Round 7
// 527.600 us; speedup vs baseline: 1.4321x; 1.0729x over previous
//
#include <hip/hip_runtime.h>

#define BB 8
#define NN 2048
#define LL 1280
#define HH 160
#define BN (BB*NN)          // 16384
#define NO (2*HH + LL)      // 1600
#define SHIFT 40.0f

typedef __attribute__((ext_vector_type(8))) short short8;
typedef __attribute__((ext_vector_type(4))) float floatx4;

__device__ __forceinline__ unsigned short f2bf(float f) {
    unsigned int u = __builtin_bit_cast(unsigned int, f);
    u = (u + 0x7FFFu + ((u >> 16) & 1u)) >> 16;
    return (unsigned short)u;
}
__device__ __forceinline__ float bf2f(unsigned short h) {
    unsigned int u = ((unsigned int)h) << 16;
    return __builtin_bit_cast(float, u);
}
__device__ __forceinline__ void split2(float f, unsigned short& hi, unsigned short& lo) {
    hi = f2bf(f);
    lo = f2bf(f - bf2f(hi));
}

// Fragment-major layouts (MFMA-native, lane = ((k>>3)&3)*16 + (row&15)):
//   q/k:  F(m,h)   = (m>>4)*2560  + (h>>5)*512   + ((h>>3)&3)*128 + (m&15)*8 + (h&7)
//   P:    F(r,tok) = (r>>4)*32768 + (tok>>5)*512 + ((tok>>3)&3)*128 + (r&15)*8 + (tok&7)
//   vt:   F(f,tok) = (f>>4)*32768 + (tok>>5)*512 + ((tok>>3)&3)*128 + (f&15)*8 + (tok&7)
// A 16-row x 32-k fragment = one contiguous 1KB wave-load / gload_lds chunk.

// ---------------- cast weights ----------------
__global__ __launch_bounds__(256) void cast_w(
    const float* __restrict__ Wq, const float* __restrict__ Wk, const float* __restrict__ Wv,
    unsigned short* __restrict__ wqk_h, unsigned short* __restrict__ wqk_l,
    unsigned short* __restrict__ wv)
{
    int o = blockIdx.x;   // 0..1599
    if (o < 2*HH) {
        const float* src = (o < HH) ? (Wq + (size_t)o * LL) : (Wk + (size_t)(o - HH) * LL);
        unsigned short* dh = wqk_h + (size_t)o * LL;
        unsigned short* dl = wqk_l + (size_t)o * LL;
        for (int c = threadIdx.x; c < LL; c += 256) {
            unsigned short h, l;
            split2(src[c], h, l);
            dh[c] = h; dl[c] = l;
        }
    } else {
        const float* src = Wv + (size_t)(o - 2*HH) * LL;
        unsigned short* dst = wv + (size_t)(o - 2*HH) * LL;
        for (int c = threadIdx.x * 4; c < LL; c += 256 * 4) {
            float4 f = *(const float4*)(src + c);
            ushort4 u;
            u.x = f2bf(f.x); u.y = f2bf(f.y); u.z = f2bf(f.z); u.w = f2bf(f.w);
            *(ushort4*)(dst + c) = u;
        }
    }
}

// ---------------- Kernel 1a: q,k projection -> frag-major q/k ----------------
__global__ __launch_bounds__(256, 2) void proj_qk(
    const float* __restrict__ x,
    const unsigned short* __restrict__ wh, const unsigned short* __restrict__ wl,
    const float* __restrict__ bq, const float* __restrict__ bk,
    unsigned short* __restrict__ qh, unsigned short* __restrict__ ql,
    unsigned short* __restrict__ kh, unsigned short* __restrict__ kl)
{
    __shared__ __align__(16) unsigned short Ah[128 * 40];
    __shared__ __align__(16) unsigned short Al[128 * 40];
    __shared__ __align__(16) unsigned short Bh[64 * 40];
    __shared__ __align__(16) unsigned short Bl[64 * 40];

    const int o0 = blockIdx.x * 64;
    const int m0 = blockIdx.y * 128;
    const int tid = threadIdx.x;
    const int wave = tid >> 6, lane = tid & 63;
    const int l15 = lane & 15, l4 = lane >> 4;

    floatx4 acc[2][4] = {};

    const int sr = tid >> 2;          // 0..63
    const int sc = (tid & 3) * 8;     // 0/8/16/24

    for (int k0 = 0; k0 < LL; k0 += 32) {
        __syncthreads();
        #pragma unroll
        for (int h = 0; h < 2; h++) {
            int r = sr + h * 64;
            const float* xp = x + (size_t)(m0 + r) * LL + k0 + sc;
            float4 f0 = *(const float4*)xp;
            float4 f1 = *(const float4*)(xp + 4);
            float fv[8] = {f0.x, f0.y, f0.z, f0.w, f1.x, f1.y, f1.z, f1.w};
            short8 h8, l8;
            #pragma unroll
            for (int i = 0; i < 8; i++) {
                unsigned short hh, lll;
                split2(fv[i], hh, lll);
                h8[i] = (short)hh; l8[i] = (short)lll;
            }
            *(short8*)&Ah[r * 40 + sc] = h8;
            *(short8*)&Al[r * 40 + sc] = l8;
        }
        *(short8*)&Bh[sr * 40 + sc] = *(const short8*)&wh[(size_t)(o0 + sr) * LL + k0 + sc];
        *(short8*)&Bl[sr * 40 + sc] = *(const short8*)&wl[(size_t)(o0 + sr) * LL + k0 + sc];
        __syncthreads();

        short8 ah0 = *(const short8*)&Ah[(wave * 32 + l15) * 40 + l4 * 8];
        short8 ah1 = *(const short8*)&Ah[(wave * 32 + 16 + l15) * 40 + l4 * 8];
        short8 al0 = *(const short8*)&Al[(wave * 32 + l15) * 40 + l4 * 8];
        short8 al1 = *(const short8*)&Al[(wave * 32 + 16 + l15) * 40 + l4 * 8];
        #pragma unroll
        for (int ct = 0; ct < 4; ct++) {
            short8 bh8 = *(const short8*)&Bh[(ct * 16 + l15) * 40 + l4 * 8];
            short8 bl8 = *(const short8*)&Bl[(ct * 16 + l15) * 40 + l4 * 8];
            acc[0][ct] = __builtin_amdgcn_mfma_f32_16x16x32_bf16(ah0, bh8, acc[0][ct], 0, 0, 0);
            acc[0][ct] = __builtin_amdgcn_mfma_f32_16x16x32_bf16(al0, bh8, acc[0][ct], 0, 0, 0);
            acc[0][ct] = __builtin_amdgcn_mfma_f32_16x16x32_bf16(ah0, bl8, acc[0][ct], 0, 0, 0);
            acc[1][ct] = __builtin_amdgcn_mfma_f32_16x16x32_bf16(ah1, bh8, acc[1][ct], 0, 0, 0);
            acc[1][ct] = __builtin_amdgcn_mfma_f32_16x16x32_bf16(al1, bh8, acc[1][ct], 0, 0, 0);
            acc[1][ct] = __builtin_amdgcn_mfma_f32_16x16x32_bf16(ah1, bl8, acc[1][ct], 0, 0, 0);
        }
    }

    #pragma unroll
    for (int rt = 0; rt < 2; rt++)
        #pragma unroll
        for (int ct = 0; ct < 4; ct++)
            #pragma unroll
            for (int r = 0; r < 4; r++) {
                int m = m0 + wave * 32 + rt * 16 + l4 * 4 + r;
                int o = o0 + ct * 16 + l15;
                float val = acc[rt][ct][r] + ((o < HH) ? bq[o] : bk[o - HH]);
                unsigned short vh, vl;
                split2(val, vh, vl);
                int oo = (o < HH) ? o : (o - HH);
                size_t fa = (size_t)(m >> 4) * 2560 + (oo >> 5) * 512
                          + ((oo >> 3) & 3) * 128 + (m & 15) * 8 + (oo & 7);
                if (o < HH) {
                    qh[fa] = vh;
                    ql[fa] = vl;
                } else {
                    kh[fa] = vh;
                    kl[fa] = vl;
                }
            }
}

// ---------------- Kernel 1b: v projection -> frag-major vt ----------------
__global__ __launch_bounds__(256, 2) void proj_v(
    const float* __restrict__ x, const unsigned short* __restrict__ wv,
    const float* __restrict__ bv, unsigned short* __restrict__ vt)
{
    __shared__ __align__(16) unsigned char smem[128 * 136 * 2];
    unsigned short* As = (unsigned short*)smem;      // [128][40]
    unsigned short* Bs = As + 128 * 40;              // [128][40]

    const int o0 = blockIdx.x * 128;
    const int m0 = blockIdx.y * 128;
    const int tid = threadIdx.x;
    const int wave = tid >> 6, lane = tid & 63;
    const int l15 = lane & 15, l4 = lane >> 4;

    floatx4 acc[2][8] = {};

    const int sr = tid >> 2;
    const int sc = (tid & 3) * 8;

    for (int k0 = 0; k0 < LL; k0 += 32) {
        __syncthreads();
        #pragma unroll
        for (int h = 0; h < 2; h++) {
            int r = sr + h * 64;
            const float* xp = x + (size_t)(m0 + r) * LL + k0 + sc;
            float4 f0 = *(const float4*)xp;
            float4 f1 = *(const float4*)(xp + 4);
            short8 h8;
            h8[0]=(short)f2bf(f0.x); h8[1]=(short)f2bf(f0.y); h8[2]=(short)f2bf(f0.z); h8[3]=(short)f2bf(f0.w);
            h8[4]=(short)f2bf(f1.x); h8[5]=(short)f2bf(f1.y); h8[6]=(short)f2bf(f1.z); h8[7]=(short)f2bf(f1.w);
            *(short8*)&As[r * 40 + sc] = h8;
            *(short8*)&Bs[r * 40 + sc] =
                *(const short8*)&wv[(size_t)(o0 + r) * LL + k0 + sc];
        }
        __syncthreads();
        short8 af0 = *(const short8*)&As[(wave * 32 + l15) * 40 + l4 * 8];
        short8 af1 = *(const short8*)&As[(wave * 32 + 16 + l15) * 40 + l4 * 8];
        #pragma unroll
        for (int ct = 0; ct < 8; ct++) {
            short8 bf = *(const short8*)&Bs[(ct * 16 + l15) * 40 + l4 * 8];
            acc[0][ct] = __builtin_amdgcn_mfma_f32_16x16x32_bf16(af0, bf, acc[0][ct], 0, 0, 0);
            acc[1][ct] = __builtin_amdgcn_mfma_f32_16x16x32_bf16(af1, bf, acc[1][ct], 0, 0, 0);
        }
    }

    __syncthreads();
    unsigned short* trs = (unsigned short*)smem;     // [128 col][136] transpose buf

    #pragma unroll
    for (int rt = 0; rt < 2; rt++)
        #pragma unroll
        for (int ct = 0; ct < 8; ct++)
            #pragma unroll
            for (int r = 0; r < 4; r++) {
                int ml = wave * 32 + rt * 16 + l4 * 4 + r;
                int cl = ct * 16 + l15;
                trs[cl * 136 + ml] = f2bf(acc[rt][ct][r] + bv[o0 + cl]);
            }
    __syncthreads();
    {
        int bidx = m0 >> 11;
        int nb0 = m0 & 2047;
        int cl = tid >> 1;
        int f = o0 + cl;
        const unsigned short* srcr = trs + cl * 136 + (tid & 1) * 64;
        unsigned short* dstF = vt + (size_t)bidx * LL * NN
                             + (size_t)(f >> 4) * 32768 + (f & 15) * 8;
        int nb = nb0 + (tid & 1) * 64;
        #pragma unroll
        for (int i = 0; i < 8; i++) {
            int n = nb + i * 8;
            *(short8*)(dstF + (size_t)(n >> 5) * 512 + ((n >> 3) & 3) * 128)
                = *(const short8*)(srcr + i * 8);
        }
    }
}

// ---------------- Kernel 2a: S = exp(QK^T - SHIFT) -> frag-major P ----------------
__global__ __launch_bounds__(256, 2) void s_exp(
    const unsigned short* __restrict__ qhp, const unsigned short* __restrict__ qlp,
    const unsigned short* __restrict__ khp, const unsigned short* __restrict__ klp,
    unsigned short* __restrict__ P, float* __restrict__ Lsum)
{
    __shared__ float sums[4][32];
    const int b  = blockIdx.y;
    const int i0 = blockIdx.x * 32;
    const int tid = threadIdx.x;
    const int wave = tid >> 6, lane = tid & 63;
    const int l15 = lane & 15, l4 = lane >> 4;

    // resident A-frags: coalesced frag-major loads
    short8 aqh[2][5], aql[2][5];
    #pragma unroll
    for (int rt = 0; rt < 2; rt++) {
        const size_t rowb = (size_t)((b * NN + i0 + rt * 16) >> 4) * 2560 + lane * 8;
        #pragma unroll
        for (int ks = 0; ks < 5; ks++) {
            aqh[rt][ks] = *(const short8*)&qhp[rowb + ks * 512];
            aql[rt][ks] = *(const short8*)&qlp[rowb + ks * 512];
        }
    }

    float sr[2][4] = {};
    unsigned short* Pb = P + (size_t)b * NN * NN + (size_t)(i0 >> 4) * 32768;

    for (int c0 = 0; c0 < NN; c0 += 256) {
        const int jb = c0 + wave * 64;      // wave's 64-col stripe
        #pragma unroll
        for (int ct = 0; ct < 4; ct++) {
            const int tok0 = jb + ct * 16;                 // multiple of 16
            const int tok  = tok0 + l15;
            const size_t kbase = (size_t)((b * NN + tok0) >> 4) * 2560 + lane * 8;
            floatx4 a0[3] = {{0,0,0,0},{0,0,0,0},{0,0,0,0}};
            floatx4 a1[3] = {{0,0,0,0},{0,0,0,0},{0,0,0,0}};
            #pragma unroll
            for (int ks = 0; ks < 5; ks++) {
                short8 bh = *(const short8*)&khp[kbase + ks * 512];
                short8 bl = *(const short8*)&klp[kbase + ks * 512];
                a0[0] = __builtin_amdgcn_mfma_f32_16x16x32_bf16(aqh[0][ks], bh, a0[0], 0, 0, 0);
                a0[1] = __builtin_amdgcn_mfma_f32_16x16x32_bf16(aql[0][ks], bh, a0[1], 0, 0, 0);
                a0[2] = __builtin_amdgcn_mfma_f32_16x16x32_bf16(aqh[0][ks], bl, a0[2], 0, 0, 0);
                a1[0] = __builtin_amdgcn_mfma_f32_16x16x32_bf16(aqh[1][ks], bh, a1[0], 0, 0, 0);
                a1[1] = __builtin_amdgcn_mfma_f32_16x16x32_bf16(aql[1][ks], bh, a1[1], 0, 0, 0);
                a1[2] = __builtin_amdgcn_mfma_f32_16x16x32_bf16(aqh[1][ks], bl, a1[2], 0, 0, 0);
            }
            // frag-major P address parts for this tok
            const size_t tbase = (size_t)(tok >> 5) * 512 + ((tok >> 3) & 3) * 128 + (tok & 7);
            #pragma unroll
            for (int r = 0; r < 4; r++) {
                float e0 = a0[0][r] + a0[1][r] + a0[2][r];
                float e1 = a1[0][r] + a1[1][r] + a1[2][r];
                unsigned short pb0 = f2bf(__expf(e0 - SHIFT));
                unsigned short pb1 = f2bf(__expf(e1 - SHIFT));
                Pb[tbase + (l4 * 4 + r) * 8] = pb0;            // rows i0..i0+15
                Pb[tbase + (l4 * 4 + r) * 8 + 32768] = pb1;    // rows i0+16..i0+31
                sr[0][r] += bf2f(pb0);
                sr[1][r] += bf2f(pb1);
            }
        }
    }

    #pragma unroll
    for (int rt = 0; rt < 2; rt++)
        #pragma unroll
        for (int r = 0; r < 4; r++) {
            float v = sr[rt][r];
            v += __shfl_xor(v, 1);
            v += __shfl_xor(v, 2);
            v += __shfl_xor(v, 4);
            v += __shfl_xor(v, 8);
            if (l15 == 0) sums[wave][rt * 16 + l4 * 4 + r] = v;
        }
    __syncthreads();
    if (tid < 32)
        Lsum[(size_t)b * NN + i0 + tid] =
            sums[0][tid] + sums[1][tid] + sums[2][tid] + sums[3][tid];
}

// ---------------- Kernel 2b v7: frag-major quadrant GEMM ----------------
// True m97 geometry: 128x128 tile, 4 waves in 2x2 quadrants of 64x64
// (acc 4x4, 8 ds_read_b128 per 16 MFMA). Frag-major P/vt makes gload_lds
// staging LINEAR (wave-uniform dest + lane*16B) and frag reads perfectly
// contiguous (lane*16B -> bank-conflict floor) with zero address VALU.
// 3-slot rotating LDS (48 KB, 3 blk/CU) + counted vmcnt(8) (T4, round-3-
// verified machinery, 4 loads/thread/tile) + setprio around MFMA (T5).
// XCD swizzle: b = bid&7 (batch per XCD), n-fastest tile order.
__device__ __forceinline__ void gl16(const unsigned short* g, unsigned short* l) {
    __builtin_amdgcn_global_load_lds(
        (const __attribute__((address_space(1))) unsigned int*)g,
        (__attribute__((address_space(3))) unsigned int*)l, 16, 0, 0);
}

__global__ __launch_bounds__(256, 3) void pv_gemm(
    const unsigned short* __restrict__ P, const unsigned short* __restrict__ vt,
    const float* __restrict__ Lsum,
    const float* __restrict__ x, float* __restrict__ out)
{
    __shared__ __align__(16) unsigned short Sm[3 * 8192];   // 48 KiB

    const int p0 = blockIdx.x;          // 0..1279
    const int b  = p0 & 7;              // one batch per XCD
    const int t  = p0 >> 3;             // 0..159
    const int n0 = (t % 10) * 128;
    const int m0 = (t / 10) * 128;

    const int tid = threadIdx.x;
    const int wave = tid >> 6, lane = tid & 63;
    const int l15 = lane & 15, l4 = lane >> 4;
    const int wm = wave >> 1, wn = wave & 1;

    const unsigned short* PbF = P  + (size_t)b * NN * NN + (size_t)(m0 >> 4) * 32768;
    const unsigned short* VbF = vt + (size_t)b * LL * NN + (size_t)(n0 >> 4) * 32768;

    // staging source offsets: chunk = p>>6 (m16/c16 group), lane-contig 16B
    const int sp0 = tid, sp1 = 256 + tid;
    const unsigned sa0 = (unsigned)(sp0 >> 6) * 32768u + (sp0 & 63) * 8;
    const unsigned sa1 = (unsigned)(sp1 >> 6) * 32768u + (sp1 & 63) * 8;

    floatx4 acc[4][4] = {};

    auto STAGE = [&](int slot, int ks) {
        unsigned short* A  = Sm + slot * 8192;
        unsigned short* Bs = A + 4096;
        const unsigned ko = (unsigned)ks * 512u;
        gl16(PbF + sa0 + ko, A  + sp0 * 8);
        gl16(VbF + sa0 + ko, Bs + sp0 * 8);
        gl16(PbF + sa1 + ko, A  + sp1 * 8);
        gl16(VbF + sa1 + ko, Bs + sp1 * 8);
    };

    auto COMPUTE = [&](int slot) {
        const unsigned short* A  = Sm + slot * 8192;
        const unsigned short* Bs = A + 4096;
        short8 a[4], bb[4];
        #pragma unroll
        for (int mf = 0; mf < 4; mf++)
            a[mf] = *(const short8*)(A + ((wm * 4 + mf) * 64 + lane) * 8);
        #pragma unroll
        for (int nf = 0; nf < 4; nf++)
            bb[nf] = *(const short8*)(Bs + ((wn * 4 + nf) * 64 + lane) * 8);
        __builtin_amdgcn_s_setprio(1);
        #pragma unroll
        for (int mf = 0; mf < 4; mf++)
            #pragma unroll
            for (int nf = 0; nf < 4; nf++)
                acc[mf][nf] = __builtin_amdgcn_mfma_f32_16x16x32_bf16(a[mf], bb[nf], acc[mf][nf], 0, 0, 0);
        __builtin_amdgcn_s_setprio(0);
    };

    // prologue: 3 tiles in flight (12 loads/thread)
    STAGE(0, 0); STAGE(1, 1); STAGE(2, 2);

    int s = 0;
    for (int kt = 0; kt < 61; ++kt) {
        asm volatile("s_waitcnt vmcnt(8)" ::: "memory");   // tile kt landed (own)
        asm volatile("s_barrier" ::: "memory");            // all waves' loads visible
        COMPUTE(s);
        asm volatile("s_barrier" ::: "memory");            // slot free for reuse
        STAGE(s, kt + 3);
        s = (s == 2) ? 0 : s + 1;
    }
    // epilogue: tiles 61,62,63 — drain 8 -> 4 -> 0
    asm volatile("s_waitcnt vmcnt(8)" ::: "memory");
    asm volatile("s_barrier" ::: "memory");
    COMPUTE(s); s = (s == 2) ? 0 : s + 1;
    asm volatile("s_waitcnt vmcnt(4)" ::: "memory");
    asm volatile("s_barrier" ::: "memory");
    COMPUTE(s); s = (s == 2) ? 0 : s + 1;
    asm volatile("s_waitcnt vmcnt(0)" ::: "memory");
    asm volatile("s_barrier" ::: "memory");
    COMPUTE(s);

    float linv[4][4];
    #pragma unroll
    for (int mf = 0; mf < 4; mf++)
        #pragma unroll
        for (int r = 0; r < 4; r++)
            linv[mf][r] = 1.0f / Lsum[(size_t)b * NN + m0 + wm * 64 + mf * 16 + l4 * 4 + r];

    #pragma unroll
    for (int mf = 0; mf < 4; mf++)
        #pragma unroll
        for (int nf = 0; nf < 4; nf++)
            #pragma unroll
            for (int r = 0; r < 4; r++) {
                int row = m0 + wm * 64 + mf * 16 + l4 * 4 + r;
                int col = n0 + wn * 64 + nf * 16 + l15;
                size_t idx = ((size_t)b * NN + row) * LL + col;
                out[idx] = acc[mf][nf][r] * linv[mf][r] + x[idx];
            }
}

extern "C" void kernel_launch(void* const* d_in, const int* in_sizes, int n_in,
                              void* d_out, int out_size, void* d_ws, size_t ws_size,
                              hipStream_t stream) {
    const float* x  = (const float*)d_in[0];
    const float* Wq = (const float*)d_in[1];
    const float* bq = (const float*)d_in[2];
    const float* Wk = (const float*)d_in[3];
    const float* bk = (const float*)d_in[4];
    const float* Wv = (const float*)d_in[5];
    const float* bv = (const float*)d_in[6];
    float* out = (float*)d_out;

    // ws layout (~135 MB)
    unsigned short* wqk_h = (unsigned short*)d_ws;            // [320][LL]
    unsigned short* wqk_l = wqk_h + (size_t)2*HH * LL;        // [320][LL]
    unsigned short* wv    = wqk_l + (size_t)2*HH * LL;        // [LL][LL]
    unsigned short* qh    = wv    + (size_t)LL * LL;          // [BN][HH] frag-major
    unsigned short* ql    = qh    + (size_t)BN * HH;
    unsigned short* kh    = ql    + (size_t)BN * HH;
    unsigned short* kl    = kh    + (size_t)BN * HH;
    unsigned short* vt    = kl    + (size_t)BN * HH;          // [BB][LL*NN] frag-major
    unsigned short* P     = vt    + (size_t)BB * LL * NN;     // [BB][NN*NN] frag-major
    float*          Lsum  = (float*)(P + (size_t)BB * NN * NN); // [BN]

    cast_w<<<dim3(NO), dim3(256), 0, stream>>>(Wq, Wk, Wv, wqk_h, wqk_l, wv);

    dim3 gqk(2*HH / 64, BN / 128);         // (5, 128)
    proj_qk<<<gqk, dim3(256), 0, stream>>>(x, wqk_h, wqk_l, bq, bk, qh, ql, kh, kl);

    dim3 gv(LL / 128, BN / 128);           // (10, 128)
    proj_v<<<gv, dim3(256), 0, stream>>>(x, wv, bv, vt);

    dim3 gs(NN / 32, BB);                  // (64, 8)
    s_exp<<<gs, dim3(256), 0, stream>>>(qh, ql, kh, kl, P, Lsum);

    // flat 1280 blocks: b = bid&7 (batch per XCD), t = bid>>3 -> (n,m) tile
    pv_gemm<<<dim3(1280), dim3(256), 0, stream>>>(P, vt, Lsum, x, out);
}

// Round 8
// 479.156 us; speedup vs baseline: 1.5769x; 1.1011x over previous
//
#include <hip/hip_runtime.h>

#define BB 8
#define NN 2048
#define LL 1280
#define HH 160
#define BN (BB*NN)          // 16384
#define NO (2*HH + LL)      // 1600
#define SHIFT 40.0f

typedef __attribute__((ext_vector_type(8))) short short8;
typedef __attribute__((ext_vector_type(4))) float floatx4;

__device__ __forceinline__ unsigned short f2bf(float f) {
    unsigned int u = __builtin_bit_cast(unsigned int, f);
    u = (u + 0x7FFFu + ((u >> 16) & 1u)) >> 16;
    return (unsigned short)u;
}
__device__ __forceinline__ float bf2f(unsigned short h) {
    unsigned int u = ((unsigned int)h) << 16;
    return __builtin_bit_cast(float, u);
}
__device__ __forceinline__ void split2(float f, unsigned short& hi, unsigned short& lo) {
    hi = f2bf(f);
    lo = f2bf(f - bf2f(hi));
}

// Fragment-major layouts (MFMA-native, lane = ((k>>3)&3)*16 + (row&15)):
//   q/k:  F(m,h)   = (m>>4)*2560  + (h>>5)*512   + ((h>>3)&3)*128 + (m&15)*8 + (h&7)
//   P:    F(r,tok) = (r>>4)*32768 + (tok>>5)*512 + ((tok>>3)&3)*128 + (r&15)*8 + (tok&7)
//   vt:   F(f,tok) = (f>>4)*32768 + (tok>>5)*512 + ((tok>>3)&3)*128 + (f&15)*8 + (tok&7)
//   xh:   F(m,k)   = (m>>4)*20480 + (k>>5)*512   + ((k>>3)&3)*128 + (m&15)*8 + (k&7)
//   wv:   F(f,k)   = (f>>4)*20480 + (k>>5)*512   + ((k>>3)&3)*128 + (f&15)*8 + (k&7)
// A 16-row x 32-k fragment = one contiguous 1KB wave-load / gload_lds chunk.

__device__ __forceinline__ void gl16(const unsigned short* g, unsigned short* l) {
    __builtin_amdgcn_global_load_lds(
        (const __attribute__((address_space(1))) unsigned int*)g,
        (__attribute__((address_space(3))) unsigned int*)l, 16, 0, 0);
}

// ---------------- cast weights ----------------
__global__ __launch_bounds__(256) void cast_w(
    const float* __restrict__ Wq, const float* __restrict__ Wk, const float* __restrict__ Wv,
    unsigned short* __restrict__ wqk_h, unsigned short* __restrict__ wqk_l,
    unsigned short* __restrict__ wv)
{
    int o = blockIdx.x;   // 0..1599
    if (o < 2*HH) {
        const float* src = (o < HH) ? (Wq + (size_t)o * LL) : (Wk + (size_t)(o - HH) * LL);
        unsigned short* dh = wqk_h + (size_t)o * LL;
        unsigned short* dl = wqk_l + (size_t)o * LL;
        for (int c = threadIdx.x; c < LL; c += 256) {
            unsigned short h, l;
            split2(src[c], h, l);
            dh[c] = h; dl[c] = l;
        }
    } else {
        // wv frag-major
        int f = o - 2*HH;
        const float* src = Wv + (size_t)f * LL;
        unsigned short* dstF = wv + (size_t)(f >> 4) * 20480 + (f & 15) * 8;
        for (int c = threadIdx.x * 4; c < LL; c += 256 * 4) {
            float4 v = *(const float4*)(src + c);
            ushort4 u;
            u.x = f2bf(v.x); u.y = f2bf(v.y); u.z = f2bf(v.z); u.w = f2bf(v.w);
            *(ushort4*)(dstF + (size_t)(c >> 5) * 512 + ((c >> 3) & 3) * 128 + (c & 7)) = u;
        }
    }
}

// ---------------- cast x -> bf16 frag-major ----------------
__global__ __launch_bounds__(256) void cast_x(
    const float* __restrict__ x, unsigned short* __restrict__ xh)
{
    const int g   = blockIdx.x;              // m16 group 0..1023
    const int tid = threadIdx.x;
    const float* src = x + (size_t)(g * 16 + (tid & 15)) * LL + ((tid >> 4) & 3) * 8;
    unsigned short* dst = xh + (size_t)g * 20480 + tid * 8;
    const int ks0 = tid >> 6;                // 0..3
    #pragma unroll
    for (int it = 0; it < 10; it++) {
        int k0 = (it * 4 + ks0) * 32;
        float4 f0 = *(const float4*)(src + k0);
        float4 f1 = *(const float4*)(src + k0 + 4);
        short8 h8;
        h8[0]=(short)f2bf(f0.x); h8[1]=(short)f2bf(f0.y); h8[2]=(short)f2bf(f0.z); h8[3]=(short)f2bf(f0.w);
        h8[4]=(short)f2bf(f1.x); h8[5]=(short)f2bf(f1.y); h8[6]=(short)f2bf(f1.z); h8[7]=(short)f2bf(f1.w);
        *(short8*)(dst + it * 2048) = h8;
    }
}

// ---------------- Kernel 1a: q,k projection -> frag-major q/k ----------------
__global__ __launch_bounds__(256, 2) void proj_qk(
    const float* __restrict__ x,
    const unsigned short* __restrict__ wh, const unsigned short* __restrict__ wl,
    const float* __restrict__ bq, const float* __restrict__ bk,
    unsigned short* __restrict__ qh, unsigned short* __restrict__ ql,
    unsigned short* __restrict__ kh, unsigned short* __restrict__ kl)
{
    __shared__ __align__(16) unsigned short Ah[128 * 40];
    __shared__ __align__(16) unsigned short Al[128 * 40];
    __shared__ __align__(16) unsigned short Bh[64 * 40];
    __shared__ __align__(16) unsigned short Bl[64 * 40];

    const int o0 = blockIdx.x * 64;
    const int m0 = blockIdx.y * 128;
    const int tid = threadIdx.x;
    const int wave = tid >> 6, lane = tid & 63;
    const int l15 = lane & 15, l4 = lane >> 4;

    floatx4 acc[2][4] = {};

    const int sr = tid >> 2;          // 0..63
    const int sc = (tid & 3) * 8;     // 0/8/16/24

    for (int k0 = 0; k0 < LL; k0 += 32) {
        __syncthreads();
        #pragma unroll
        for (int h = 0; h < 2; h++) {
            int r = sr + h * 64;
            const float* xp = x + (size_t)(m0 + r) * LL + k0 + sc;
            float4 f0 = *(const float4*)xp;
            float4 f1 = *(const float4*)(xp + 4);
            float fv[8] = {f0.x, f0.y, f0.z, f0.w, f1.x, f1.y, f1.z, f1.w};
            short8 h8, l8;
            #pragma unroll
            for (int i = 0; i < 8; i++) {
                unsigned short hh, lll;
                split2(fv[i], hh, lll);
                h8[i] = (short)hh; l8[i] = (short)lll;
            }
            *(short8*)&Ah[r * 40 + sc] = h8;
            *(short8*)&Al[r * 40 + sc] = l8;
        }
        *(short8*)&Bh[sr * 40 + sc] = *(const short8*)&wh[(size_t)(o0 + sr) * LL + k0 + sc];
        *(short8*)&Bl[sr * 40 + sc] = *(const short8*)&wl[(size_t)(o0 + sr) * LL + k0 + sc];
        __syncthreads();

        short8 ah0 = *(const short8*)&Ah[(wave * 32 + l15) * 40 + l4 * 8];
        short8 ah1 = *(const short8*)&Ah[(wave * 32 + 16 + l15) * 40 + l4 * 8];
        short8 al0 = *(const short8*)&Al[(wave * 32 + l15) * 40 + l4 * 8];
        short8 al1 = *(const short8*)&Al[(wave * 32 + 16 + l15) * 40 + l4 * 8];
        #pragma unroll
        for (int ct = 0; ct < 4; ct++) {
            short8 bh8 = *(const short8*)&Bh[(ct * 16 + l15) * 40 + l4 * 8];
            short8 bl8 = *(const short8*)&Bl[(ct * 16 + l15) * 40 + l4 * 8];
            acc[0][ct] = __builtin_amdgcn_mfma_f32_16x16x32_bf16(ah0, bh8, acc[0][ct], 0, 0, 0);
            acc[0][ct] = __builtin_amdgcn_mfma_f32_16x16x32_bf16(al0, bh8, acc[0][ct], 0, 0, 0);
            acc[0][ct] = __builtin_amdgcn_mfma_f32_16x16x32_bf16(ah0, bl8, acc[0][ct], 0, 0, 0);
            acc[1][ct] = __builtin_amdgcn_mfma_f32_16x16x32_bf16(ah1, bh8, acc[1][ct], 0, 0, 0);
            acc[1][ct] = __builtin_amdgcn_mfma_f32_16x16x32_bf16(al1, bh8, acc[1][ct], 0, 0, 0);
            acc[1][ct] = __builtin_amdgcn_mfma_f32_16x16x32_bf16(ah1, bl8, acc[1][ct], 0, 0, 0);
        }
    }

    #pragma unroll
    for (int rt = 0; rt < 2; rt++)
        #pragma unroll
        for (int ct = 0; ct < 4; ct++)
            #pragma unroll
            for (int r = 0; r < 4; r++) {
                int m = m0 + wave * 32 + rt * 16 + l4 * 4 + r;
                int o = o0 + ct * 16 + l15;
                float val = acc[rt][ct][r] + ((o < HH) ? bq[o] : bk[o - HH]);
                unsigned short vh, vl;
                split2(val, vh, vl);
                int oo = (o < HH) ? o : (o - HH);
                size_t fa = (size_t)(m >> 4) * 2560 + (oo >> 5) * 512
                          + ((oo >> 3) & 3) * 128 + (m & 15) * 8 + (oo & 7);
                if (o < HH) {
                    qh[fa] = vh;
                    ql[fa] = vl;
                } else {
                    kh[fa] = vh;
                    kl[fa] = vl;
                }
            }
}

// ---------------- Kernel 1b v2: v projection, v7 quadrant pipeline ----------------
// Same machine as pv_gemm v7: 128x128 tile (m x f), 2x2 wave quadrants of
// 64x64 (acc 4x4), 3-slot rotating LDS (48 KB), counted vmcnt(8), setprio.
// A = xh frag-major, B = wv frag-major (both gload_lds LINEAR). K=1280 ->
// 40 steps. Epilogue: bias + direct frag-major ushort4 stores into vt (no
// LDS transpose -> no bank conflicts). Grid: xcd = bid&7 owns batch xcd
// (m_tile = xcd*16 + q/10), f-fastest -> x panel fetched once per XCD.
__global__ __launch_bounds__(256, 3) void proj_v(
    const unsigned short* __restrict__ xh, const unsigned short* __restrict__ wv,
    const float* __restrict__ bv, unsigned short* __restrict__ vt)
{
    __shared__ __align__(16) unsigned short Sm[3 * 8192];   // 48 KiB

    const int bid = blockIdx.x;         // 0..1279
    const int xcd = bid & 7;
    const int q   = bid >> 3;           // 0..159
    const int mt  = xcd * 16 + q / 10;  // m-tile 0..127 (batch = xcd)
    const int ft  = q % 10;             // f-tile 0..9
    const int m0 = mt * 128;
    const int f0 = ft * 128;

    const int tid = threadIdx.x;
    const int wave = tid >> 6, lane = tid & 63;
    const int l15 = lane & 15, l4 = lane >> 4;
    const int wm = wave >> 1, wn = wave & 1;

    const unsigned short* AF = xh + (size_t)(m0 >> 4) * 20480;
    const unsigned short* BF = wv + (size_t)(f0 >> 4) * 20480;

    const int sp0 = tid, sp1 = 256 + tid;
    const unsigned sa0 = (unsigned)(sp0 >> 6) * 20480u + (sp0 & 63) * 8;
    const unsigned sa1 = (unsigned)(sp1 >> 6) * 20480u + (sp1 & 63) * 8;

    floatx4 acc[4][4] = {};

    auto STAGE = [&](int slot, int ks) {
        unsigned short* A  = Sm + slot * 8192;
        unsigned short* Bs = A + 4096;
        const unsigned ko = (unsigned)ks * 512u;
        gl16(AF + sa0 + ko, A  + sp0 * 8);
        gl16(BF + sa0 + ko, Bs + sp0 * 8);
        gl16(AF + sa1 + ko, A  + sp1 * 8);
        gl16(BF + sa1 + ko, Bs + sp1 * 8);
    };

    auto COMPUTE = [&](int slot) {
        const unsigned short* A  = Sm + slot * 8192;
        const unsigned short* Bs = A + 4096;
        short8 a[4], bb[4];
        #pragma unroll
        for (int mf = 0; mf < 4; mf++)
            a[mf] = *(const short8*)(A + ((wm * 4 + mf) * 64 + lane) * 8);
        #pragma unroll
        for (int nf = 0; nf < 4; nf++)
            bb[nf] = *(const short8*)(Bs + ((wn * 4 + nf) * 64 + lane) * 8);
        __builtin_amdgcn_s_setprio(1);
        #pragma unroll
        for (int mf = 0; mf < 4; mf++)
            #pragma unroll
            for (int nf = 0; nf < 4; nf++)
                acc[mf][nf] = __builtin_amdgcn_mfma_f32_16x16x32_bf16(a[mf], bb[nf], acc[mf][nf], 0, 0, 0);
        __builtin_amdgcn_s_setprio(0);
    };

    STAGE(0, 0); STAGE(1, 1); STAGE(2, 2);

    int s = 0;
    for (int kt = 0; kt < 37; ++kt) {              // 40 K-steps total
        asm volatile("s_waitcnt vmcnt(8)" ::: "memory");
        asm volatile("s_barrier" ::: "memory");
        COMPUTE(s);
        asm volatile("s_barrier" ::: "memory");
        STAGE(s, kt + 3);
        s = (s == 2) ? 0 : s + 1;
    }
    asm volatile("s_waitcnt vmcnt(8)" ::: "memory");
    asm volatile("s_barrier" ::: "memory");
    COMPUTE(s); s = (s == 2) ? 0 : s + 1;
    asm volatile("s_waitcnt vmcnt(4)" ::: "memory");
    asm volatile("s_barrier" ::: "memory");
    COMPUTE(s); s = (s == 2) ? 0 : s + 1;
    asm volatile("s_waitcnt vmcnt(0)" ::: "memory");
    asm volatile("s_barrier" ::: "memory");
    COMPUTE(s);

    // epilogue: bias + direct frag-major vt stores (ushort4 over r)
    const int b    = m0 >> 11;                    // == xcd
    const int tokb = (m0 & 2047) + wm * 64;
    unsigned short* vtB = vt + (size_t)b * LL * NN;
    float bvv[4];
    #pragma unroll
    for (int nf = 0; nf < 4; nf++)
        bvv[nf] = bv[f0 + wn * 64 + nf * 16 + l15];

    #pragma unroll
    for (int mf = 0; mf < 4; mf++)
        #pragma unroll
        for (int nf = 0; nf < 4; nf++) {
            int f   = f0 + wn * 64 + nf * 16 + l15;
            int tok = tokb + mf * 16 + l4 * 4;    // +r, r=0..3 contiguous in (tok&7)
            ushort4 u;
            u.x = f2bf(acc[mf][nf][0] + bvv[nf]);
            u.y = f2bf(acc[mf][nf][1] + bvv[nf]);
            u.z = f2bf(acc[mf][nf][2] + bvv[nf]);
            u.w = f2bf(acc[mf][nf][3] + bvv[nf]);
            *(ushort4*)(vtB + (size_t)(f >> 4) * 32768 + (tok >> 5) * 512
                        + ((tok >> 3) & 3) * 128 + (f & 15) * 8 + (tok & 7)) = u;
        }
}

// ---------------- Kernel 2a: S = exp(QK^T - SHIFT) -> frag-major P ----------------
__global__ __launch_bounds__(256, 2) void s_exp(
    const unsigned short* __restrict__ qhp, const unsigned short* __restrict__ qlp,
    const unsigned short* __restrict__ khp, const unsigned short* __restrict__ klp,
    unsigned short* __restrict__ P, float* __restrict__ Lsum)
{
    __shared__ float sums[4][32];
    const int b  = blockIdx.y;
    const int i0 = blockIdx.x * 32;
    const int tid = threadIdx.x;
    const int wave = tid >> 6, lane = tid & 63;
    const int l15 = lane & 15, l4 = lane >> 4;

    // resident A-frags: coalesced frag-major loads
    short8 aqh[2][5], aql[2][5];
    #pragma unroll
    for (int rt = 0; rt < 2; rt++) {
        const size_t rowb = (size_t)((b * NN + i0 + rt * 16) >> 4) * 2560 + lane * 8;
        #pragma unroll
        for (int ks = 0; ks < 5; ks++) {
            aqh[rt][ks] = *(const short8*)&qhp[rowb + ks * 512];
            aql[rt][ks] = *(const short8*)&qlp[rowb + ks * 512];
        }
    }

    float sr[2][4] = {};
    unsigned short* Pb = P + (size_t)b * NN * NN + (size_t)(i0 >> 4) * 32768;

    for (int c0 = 0; c0 < NN; c0 += 256) {
        const int jb = c0 + wave * 64;      // wave's 64-col stripe
        #pragma unroll
        for (int ct = 0; ct < 4; ct++) {
            const int tok0 = jb + ct * 16;                 // multiple of 16
            const int tok  = tok0 + l15;
            const size_t kbase = (size_t)((b * NN + tok0) >> 4) * 2560 + lane * 8;
            floatx4 a0[3] = {{0,0,0,0},{0,0,0,0},{0,0,0,0}};
            floatx4 a1[3] = {{0,0,0,0},{0,0,0,0},{0,0,0,0}};
            #pragma unroll
            for (int ks = 0; ks < 5; ks++) {
                short8 bh = *(const short8*)&khp[kbase + ks * 512];
                short8 bl = *(const short8*)&klp[kbase + ks * 512];
                a0[0] = __builtin_amdgcn_mfma_f32_16x16x32_bf16(aqh[0][ks], bh, a0[0], 0, 0, 0);
                a0[1] = __builtin_amdgcn_mfma_f32_16x16x32_bf16(aql[0][ks], bh, a0[1], 0, 0, 0);
                a0[2] = __builtin_amdgcn_mfma_f32_16x16x32_bf16(aqh[0][ks], bl, a0[2], 0, 0, 0);
                a1[0] = __builtin_amdgcn_mfma_f32_16x16x32_bf16(aqh[1][ks], bh, a1[0], 0, 0, 0);
                a1[1] = __builtin_amdgcn_mfma_f32_16x16x32_bf16(aql[1][ks], bh, a1[1], 0, 0, 0);
                a1[2] = __builtin_amdgcn_mfma_f32_16x16x32_bf16(aqh[1][ks], bl, a1[2], 0, 0, 0);
            }
            // frag-major P address parts for this tok
            const size_t tbase = (size_t)(tok >> 5) * 512 + ((tok >> 3) & 3) * 128 + (tok & 7);
            #pragma unroll
            for (int r = 0; r < 4; r++) {
                float e0 = a0[0][r] + a0[1][r] + a0[2][r];
                float e1 = a1[0][r] + a1[1][r] + a1[2][r];
                unsigned short pb0 = f2bf(__expf(e0 - SHIFT));
                unsigned short pb1 = f2bf(__expf(e1 - SHIFT));
                Pb[tbase + (l4 * 4 + r) * 8] = pb0;            // rows i0..i0+15
                Pb[tbase + (l4 * 4 + r) * 8 + 32768] = pb1;    // rows i0+16..i0+31
                sr[0][r] += bf2f(pb0);
                sr[1][r] += bf2f(pb1);
            }
        }
    }

    #pragma unroll
    for (int rt = 0; rt < 2; rt++)
        #pragma unroll
        for (int r = 0; r < 4; r++) {
            float v = sr[rt][r];
            v += __shfl_xor(v, 1);
            v += __shfl_xor(v, 2);
            v += __shfl_xor(v, 4);
            v += __shfl_xor(v, 8);
            if (l15 == 0) sums[wave][rt * 16 + l4 * 4 + r] = v;
        }
    __syncthreads();
    if (tid < 32)
        Lsum[(size_t)b * NN + i0 + tid] =
            sums[0][tid] + sums[1][tid] + sums[2][tid] + sums[3][tid];
}

// ---------------- Kernel 2b v7: frag-major quadrant GEMM ----------------
__global__ __launch_bounds__(256, 3) void pv_gemm(
    const unsigned short* __restrict__ P, const unsigned short* __restrict__ vt,
    const float* __restrict__ Lsum,
    const float* __restrict__ x, float* __restrict__ out)
{
    __shared__ __align__(16) unsigned short Sm[3 * 8192];   // 48 KiB

    const int p0 = blockIdx.x;          // 0..1279
    const int b  = p0 & 7;              // one batch per XCD
    const int t  = p0 >> 3;             // 0..159
    const int n0 = (t % 10) * 128;
    const int m0 = (t / 10) * 128;

    const int tid = threadIdx.x;
    const int wave = tid >> 6, lane = tid & 63;
    const int l15 = lane & 15, l4 = lane >> 4;
    const int wm = wave >> 1, wn = wave & 1;

    const unsigned short* PbF = P  + (size_t)b * NN * NN + (size_t)(m0 >> 4) * 32768;
    const unsigned short* VbF = vt + (size_t)b * LL * NN + (size_t)(n0 >> 4) * 32768;

    const int sp0 = tid, sp1 = 256 + tid;
    const unsigned sa0 = (unsigned)(sp0 >> 6) * 32768u + (sp0 & 63) * 8;
    const unsigned sa1 = (unsigned)(sp1 >> 6) * 32768u + (sp1 & 63) * 8;

    floatx4 acc[4][4] = {};

    auto STAGE = [&](int slot, int ks) {
        unsigned short* A  = Sm + slot * 8192;
        unsigned short* Bs = A + 4096;
        const unsigned ko = (unsigned)ks * 512u;
        gl16(PbF + sa0 + ko, A  + sp0 * 8);
        gl16(VbF + sa0 + ko, Bs + sp0 * 8);
        gl16(PbF + sa1 + ko, A  + sp1 * 8);
        gl16(VbF + sa1 + ko, Bs + sp1 * 8);
    };

    auto COMPUTE = [&](int slot) {
        const unsigned short* A  = Sm + slot * 8192;
        const unsigned short* Bs = A + 4096;
        short8 a[4], bb[4];
        #pragma unroll
        for (int mf = 0; mf < 4; mf++)
            a[mf] = *(const short8*)(A + ((wm * 4 + mf) * 64 + lane) * 8);
        #pragma unroll
        for (int nf = 0; nf < 4; nf++)
            bb[nf] = *(const short8*)(Bs + ((wn * 4 + nf) * 64 + lane) * 8);
        __builtin_amdgcn_s_setprio(1);
        #pragma unroll
        for (int mf = 0; mf < 4; mf++)
            #pragma unroll
            for (int nf = 0; nf < 4; nf++)
                acc[mf][nf] = __builtin_amdgcn_mfma_f32_16x16x32_bf16(a[mf], bb[nf], acc[mf][nf], 0, 0, 0);
        __builtin_amdgcn_s_setprio(0);
    };

    STAGE(0, 0); STAGE(1, 1); STAGE(2, 2);

    int s = 0;
    for (int kt = 0; kt < 61; ++kt) {
        asm volatile("s_waitcnt vmcnt(8)" ::: "memory");
        asm volatile("s_barrier" ::: "memory");
        COMPUTE(s);
        asm volatile("s_barrier" ::: "memory");
        STAGE(s, kt + 3);
        s = (s == 2) ? 0 : s + 1;
    }
    asm volatile("s_waitcnt vmcnt(8)" ::: "memory");
    asm volatile("s_barrier" ::: "memory");
    COMPUTE(s); s = (s == 2) ? 0 : s + 1;
    asm volatile("s_waitcnt vmcnt(4)" ::: "memory");
    asm volatile("s_barrier" ::: "memory");
    COMPUTE(s); s = (s == 2) ? 0 : s + 1;
    asm volatile("s_waitcnt vmcnt(0)" ::: "memory");
    asm volatile("s_barrier" ::: "memory");
    COMPUTE(s);

    float linv[4][4];
    #pragma unroll
    for (int mf = 0; mf < 4; mf++)
        #pragma unroll
        for (int r = 0; r < 4; r++)
            linv[mf][r] = 1.0f / Lsum[(size_t)b * NN + m0 + wm * 64 + mf * 16 + l4 * 4 + r];

    #pragma unroll
    for (int mf = 0; mf < 4; mf++)
        #pragma unroll
        for (int nf = 0; nf < 4; nf++)
            #pragma unroll
            for (int r = 0; r < 4; r++) {
                int row = m0 + wm * 64 + mf * 16 + l4 * 4 + r;
                int col = n0 + wn * 64 + nf * 16 + l15;
                size_t idx = ((size_t)b * NN + row) * LL + col;
                out[idx] = acc[mf][nf][r] * linv[mf][r] + x[idx];
            }
}

extern "C" void kernel_launch(void* const* d_in, const int* in_sizes, int n_in,
                              void* d_out, int out_size, void* d_ws, size_t ws_size,
                              hipStream_t stream) {
    const float* x  = (const float*)d_in[0];
    const float* Wq = (const float*)d_in[1];
    const float* bq = (const float*)d_in[2];
    const float* Wk = (const float*)d_in[3];
    const float* bk = (const float*)d_in[4];
    const float* Wv = (const float*)d_in[5];
    const float* bv = (const float*)d_in[6];
    float* out = (float*)d_out;

    // ws layout (~135 MB)
    unsigned short* wqk_h = (unsigned short*)d_ws;            // [320][LL]
    unsigned short* wqk_l = wqk_h + (size_t)2*HH * LL;        // [320][LL]
    unsigned short* wv    = wqk_l + (size_t)2*HH * LL;        // [LL*LL] frag-major
    unsigned short* qh    = wv    + (size_t)LL * LL;          // [BN][HH] frag-major
    unsigned short* ql    = qh    + (size_t)BN * HH;
    unsigned short* kh    = ql    + (size_t)BN * HH;
    unsigned short* kl    = kh    + (size_t)BN * HH;
    unsigned short* vt    = kl    + (size_t)BN * HH;          // [BB][LL*NN] frag-major
    unsigned short* P     = vt    + (size_t)BB * LL * NN;     // [BB][NN*NN] frag-major
    float*          Lsum  = (float*)(P + (size_t)BB * NN * NN); // [BN]
    // xh (bf16 frag-major x, 42 MB) ALIASES P (67 MB): xh is consumed by
    // proj_v, which completes before s_exp writes P (same stream).
    unsigned short* xh    = P;

    cast_w<<<dim3(NO), dim3(256), 0, stream>>>(Wq, Wk, Wv, wqk_h, wqk_l, wv);

    cast_x<<<dim3(BN / 16), dim3(256), 0, stream>>>(x, xh);

    dim3 gqk(2*HH / 64, BN / 128);         // (5, 128)
    proj_qk<<<gqk, dim3(256), 0, stream>>>(x, wqk_h, wqk_l, bq, bk, qh, ql, kh, kl);

    // flat 1280 blocks: xcd = bid&7 owns batch xcd; f-fastest within XCD
    proj_v<<<dim3(1280), dim3(256), 0, stream>>>(xh, wv, bv, vt);

    dim3 gs(NN / 32, BB);                  // (64, 8)
    s_exp<<<gs, dim3(256), 0, stream>>>(qh, ql, kh, kl, P, Lsum);

    // flat 1280 blocks: b = bid&7 (batch per XCD), t = bid>>3 -> (n,m) tile
    pv_gemm<<<dim3(1280), dim3(256), 0, stream>>>(P, vt, Lsum, x, out);
}